// Round 13
// baseline (265.482 us; speedup 1.0000x reference)
//
#include <hip/hip_runtime.h>
#include <math.h>

#define HB 8
#define KD 64
#define VD 192
#define BT 2
#define TT 1536
#define CC 1536
#define HK (HB*KD)   // 512
#define HV (HB*VD)   // 1536
#define QKVP 2560    // fused qkv row pitch: q[0:512) k[512:1024) v[1024:2560)
#define LOG2E 1.44269504088896340736f

typedef float f32x4 __attribute__((ext_vector_type(4)));
typedef __bf16 bf16x8 __attribute__((ext_vector_type(8)));

static __device__ __forceinline__ ushort f2bf(float f) {
  union { float f; uint u; } v; v.f = f;
  uint r = (v.u + 0x7FFFu + ((v.u >> 16) & 1u)) >> 16;  // RNE
  return (ushort)r;
}
static __device__ __forceinline__ float bf2f(ushort u) {
  union { uint u; float f; } v; v.u = ((uint)u) << 16; return v.f;
}

static __device__ __forceinline__ f32x4 mfma_bf(bf16x8 a, bf16x8 b, f32x4 c) {
  return __builtin_amdgcn_mfma_f32_16x16x32_bf16(a, b, c, 0, 0, 0);
}

static __device__ __forceinline__ void gload_lds16(const ushort* g, ushort* l) {
  __builtin_amdgcn_global_load_lds(
      (const __attribute__((address_space(1))) unsigned int*)g,
      (__attribute__((address_space(3))) unsigned int*)l, 16, 0, 0);
}

__device__ __forceinline__ void storeC(float* p, float v) { *p = v; }
__device__ __forceinline__ void storeC(ushort* p, float v) { *p = f2bf(v); }

// ---------------- cast fp32 -> bf16 (vectorized) ----------------
__global__ __launch_bounds__(256) void cast_bf16(
    const float* __restrict__ in, ushort* __restrict__ out, int n4)
{
  for (int i = blockIdx.x*blockDim.x + threadIdx.x; i < n4; i += gridDim.x*blockDim.x) {
    float4 v = ((const float4*)in)[i];
    ushort4 o; o.x = f2bf(v.x); o.y = f2bf(v.y); o.z = f2bf(v.z); o.w = f2bf(v.w);
    ((ushort4*)out)[i] = o;
  }
}

// ---------------- transpose + cast + scale: in[R][C] fp32 -> out[C][R] bf16 ----------------
__global__ void tcast(const float* __restrict__ in, ushort* __restrict__ out, int R, int C, float scale)
{
  __shared__ float tile[32][33];
  const int bx = blockIdx.x * 32;
  const int by = blockIdx.y * 32;
  const int tx = threadIdx.x, ty = threadIdx.y;  // (32,8)
  #pragma unroll
  for (int i = 0; i < 4; ++i)
    tile[ty + i*8][tx] = in[(size_t)(by + ty + i*8)*C + bx + tx];
  __syncthreads();
  #pragma unroll
  for (int i = 0; i < 4; ++i)
    out[(size_t)(bx + ty + i*8)*R + by + tx] = f2bf(tile[tx][ty + i*8] * scale);
}

// ---------------- bf16 transpose of V section: qkv[key][1024+vd] -> vTg[vd][key] ----------------
__global__ void vtrans(const ushort* __restrict__ in, ushort* __restrict__ out)
{
  __shared__ ushort tile[32][33];
  const int bx = blockIdx.x * 32;  // vd base
  const int by = blockIdx.y * 32;  // key base
  const int tx = threadIdx.x, ty = threadIdx.y;  // (32,8)
  #pragma unroll
  for (int i = 0; i < 4; ++i)
    tile[ty + i*8][tx] = in[(size_t)(by + ty + i*8)*QKVP + 1024 + bx + tx];
  __syncthreads();
  #pragma unroll
  for (int i = 0; i < 4; ++i)
    out[(size_t)(bx + ty + i*8)*(BT*TT) + by + tx] = tile[tx][ty + i*8];
}

// ---------------- bf16 MFMA GEMM: C[M,N] = A[M,Kd] @ Bt[N,Kd]^T (+bias) ----------------
template<bool WITH_BIAS, typename OutT>
__global__ __launch_bounds__(256) void gemm_bf16(
    const ushort* __restrict__ A, const ushort* __restrict__ Bt,
    const float* __restrict__ bias, OutT* __restrict__ C,
    int M, int N, int Kd)
{
  __shared__ __align__(16) ushort As[128*64];
  __shared__ __align__(16) ushort Bs[128*64];
  const int t = threadIdx.x;
  const int w = t >> 6, lane = t & 63;
  const int lrow = lane & 15, lk8 = lane >> 4;
  const int row0 = blockIdx.y * 128, col0 = blockIdx.x * 128;
  const int wr = (w >> 1) * 64, wc = (w & 1) * 64;

  f32x4 acc[4][4];
  #pragma unroll
  for (int m = 0; m < 4; ++m)
    #pragma unroll
    for (int n = 0; n < 4; ++n) acc[m][n] = (f32x4){0.f,0.f,0.f,0.f};

  for (int k0 = 0; k0 < Kd; k0 += 64) {
    __syncthreads();
    #pragma unroll
    for (int j = 0; j < 4; ++j) {
      const int c = (w*4 + j)*64 + lane;
      const int r = c >> 3, cp = c & 7;
      const int sc = cp ^ (r & 7);
      gload_lds16(A  + (size_t)(row0 + r)*Kd + k0 + sc*8, As + c*8);
      gload_lds16(Bt + (size_t)(col0 + r)*Kd + k0 + sc*8, Bs + c*8);
    }
    __syncthreads();
    bf16x8 af[4][2], bfv[4][2];
    #pragma unroll
    for (int m = 0; m < 4; ++m) {
      const int r = wr + m*16 + lrow;
      #pragma unroll
      for (int kh = 0; kh < 2; ++kh) {
        const int k8 = lk8 + kh*4;
        af[m][kh] = *(const bf16x8*)&As[r*64 + ((k8 ^ (r & 7)) << 3)];
      }
    }
    #pragma unroll
    for (int n = 0; n < 4; ++n) {
      const int r = wc + n*16 + lrow;
      #pragma unroll
      for (int kh = 0; kh < 2; ++kh) {
        const int k8 = lk8 + kh*4;
        bfv[n][kh] = *(const bf16x8*)&Bs[r*64 + ((k8 ^ (r & 7)) << 3)];
      }
    }
    #pragma unroll
    for (int m = 0; m < 4; ++m)
      #pragma unroll
      for (int n = 0; n < 4; ++n) {
        acc[m][n] = mfma_bf(af[m][0], bfv[n][0], acc[m][n]);
        acc[m][n] = mfma_bf(af[m][1], bfv[n][1], acc[m][n]);
      }
  }
  #pragma unroll
  for (int m = 0; m < 4; ++m)
    #pragma unroll
    for (int n = 0; n < 4; ++n) {
      const int cg = col0 + wc + n*16 + lrow;
      const float bb = WITH_BIAS ? bias[cg] : 0.f;
      #pragma unroll
      for (int r = 0; r < 4; ++r) {
        const int rg = row0 + wr + m*16 + lk8*4 + r;
        storeC(&C[(size_t)rg*N + cg], acc[m][n][r] + bb);
      }
    }
}

// ---------------- Wrk suffix sums ----------------
__global__ __launch_bounds__(256) void wrk_suffix(
    const float* __restrict__ Wrk, float* __restrict__ S1, float* __restrict__ S2)
{
  const int c = blockIdx.x*blockDim.x + threadIdx.x;
  float a1 = 0.f, a2 = 0.f;
  S1[96*HK + c] = 0.f; S2[96*HK + c] = 0.f;
  for (int i = 95; i >= 0; --i) {
    a1 += Wrk[i*HK + c];
    a2 += Wrk[(96 + i)*HK + c];
    S1[i*HK + c] = a1; S2[i*HK + c] = a2;
  }
}

// ---------------- rk[m][c] bf16 + c2[h][m] = (rrb_h . rk[m]) * log2e ----------------
__global__ __launch_bounds__(256) void relk_fill(
    const float* __restrict__ S1, const float* __restrict__ S2,
    const float* __restrict__ rrb, ushort* __restrict__ rk, float* __restrict__ c2g)
{
  __shared__ float cw[96];
  __shared__ float red[512];
  __shared__ int i0s;
  const int t = threadIdx.x;
  const int m = blockIdx.x;            // 0 .. 2T-2
  if (t < 96) {
    double pr = exp(log((double)(TT + 1)) / 96.0);
    float prf = (float)pr;
    cw[t] = (float)pow((double)prf, (double)(t + 1)) - 1.0f;
  }
  __syncthreads();
  const int d = m - (TT - 1);
  const float ad = fabsf((float)d);
  if (t == 0) {
    int i0 = 96;
    for (int i = 0; i < 96; ++i) if (cw[i] > ad) { i0 = i; break; }
    i0s = i0;
  }
  __syncthreads();
  const float sg = (d > 0) ? 1.f : (d < 0 ? -1.f : 0.f);
  const int i0 = i0s;
  for (int c = t; c < HK; c += 256) {
    const float val = S1[i0*HK + c] + sg * S2[i0*HK + c];
    const ushort vb = f2bf(val);
    rk[(size_t)m * HK + c] = vb;
    red[c] = bf2f(vb) * rrb[c];
  }
  __syncthreads();
  if (t < 8) {
    float s = 0.f;
    #pragma unroll 16
    for (int i = 0; i < 64; ++i) s += red[t*64 + i];
    c2g[(size_t)t*(2*TT - 1) + m] = s * LOG2E;
  }
}

// ---------------- c1[h][row] = (rwb_h . k[row]) * log2e ----------------
__global__ __launch_bounds__(256) void c1_kernel(
    const ushort* __restrict__ qkv, const float* __restrict__ rwb, float* __restrict__ c1g)
{
  const int idx = blockIdx.x*256 + threadIdx.x;  // 3072*8
  const int h = idx & 7, row = idx >> 3;
  const ushort* kr = &qkv[(size_t)row*QKVP + 512 + h*KD];
  float s = 0.f;
  #pragma unroll 16
  for (int c = 0; c < 64; ++c) s += bf2f(kr[c]) * rwb[h*KD + c];
  c1g[h*(BT*TT) + row] = s * LOG2E;
}

// ---------------- fused relative attention: KBLK=64, 8 waves, shift-on-write S2, XCD swizzle ----------------
__global__ __launch_bounds__(512, 4) void attn_mfma(
    const ushort* __restrict__ qkv, const ushort* __restrict__ vTg,
    const ushort* __restrict__ rk,
    const float* __restrict__ c1g, const float* __restrict__ c2g,
    ushort* __restrict__ aout)
{
  __shared__ __align__(16) ushort ktL[64*64];    // k tile (8 KB)
  __shared__ __align__(16) ushort rkbL[96*64];   // rk band, all 96 rows staged (12 KB)
  __shared__ __align__(16) ushort vTl[192*64];   // vT tile (24 KB)
  __shared__ __align__(16) ushort Pl[32][72];    // P bf16 (4.5 KB)
  __shared__ __align__(16) float S1[32][68];     // content logits (8.5 KB)
  __shared__ __align__(16) float S2s[32][68];    // rel logits, PRE-SHIFTED (8.5 KB)
  __shared__ float corrl[32], linv[32];

  const int t = threadIdx.x;          // 0..511
  const int wv = t >> 6, lane = t & 63;
  const int lrow = lane & 15, lk8 = lane >> 4;
  const int bid = blockIdx.x;
  const int qt = bid >> 4;            // XCD swizzle: bid%8 == h
  const int h  = bid & 7;
  const int b  = (bid >> 3) & 1;
  const int q0 = qt * 32;

  // q A-fragments (loop-invariant)
  bf16x8 af00, af01, af10, af11;
  {
    const ushort* qb0 = &qkv[((size_t)(b*TT) + q0 + lrow)*QKVP + h*KD];
    af00 = *(const bf16x8*)&qb0[lk8*8];
    af01 = *(const bf16x8*)&qb0[32 + lk8*8];
    af10 = *(const bf16x8*)&qb0[16*QKVP + lk8*8];
    af11 = *(const bf16x8*)&qb0[16*QKVP + 32 + lk8*8];
  }

  // ---- S-phase tile descriptors: tiles idx = wv + 8*s, 20 tiles total ----
  int rtT[3], colT[3]; bool isS1T[3], validT[3];
  #pragma unroll
  for (int s = 0; s < 3; ++s) {
    int idx = wv + 8*s;
    validT[s] = (idx < 20);
    if (idx > 19) idx = 19;
    if (idx < 8) { isS1T[s] = true;  rtT[s] = idx >> 2; colT[s] = (idx & 3)*16 + lrow; }
    else { const int k = idx - 8; isS1T[s] = false; rtT[s] = k/6; colT[s] = (k%6)*16 + lrow; }
  }

  // ---- per-thread staging pointers: UNIFORM 3 loads/wave (fix for r12 coverage hole) ----
  // waves 0-3: all 768 rkb chunks (3 each); waves 4-7: all 512 k chunks (2 each) + 1 duplicate.
  const ushort* sp[3]; ushort* sd[3]; size_t sstep;
  if (t < 256) {
    sstep = (size_t)64*HK;
    #pragma unroll
    for (int W = 0; W < 3; ++W) {
      const int c = W*256 + t, r = c >> 3, cp = c & 7;
      sp[W] = rk + (size_t)(1504 - q0 + r)*HK + h*KD + (cp ^ (r & 7))*8;
      sd[W] = rkbL + c*8;
    }
  } else {
    sstep = (size_t)64*QKVP;
    #pragma unroll
    for (int W = 0; W < 2; ++W) {
      const int c = W*256 + (t - 256), r = c >> 3, cp = c & 7;
      sp[W] = qkv + (size_t)(b*TT + r)*QKVP + 512 + h*KD + (cp ^ (r & 7))*8;
      sd[W] = ktL + c*8;
    }
    sp[2] = sp[0]; sd[2] = sd[0];   // duplicate (same bytes, same dst) keeps counts uniform
  }
  const ushort* vsrc[3]; ushort* vdst[3];
  #pragma unroll
  for (int W = 0; W < 3; ++W) {
    const int c = W*512 + t, vd = c >> 3, cpk = c & 7;
    vsrc[W] = vTg + (size_t)(h*VD + vd)*(BT*TT) + b*TT + (cpk ^ (vd & 7))*8;
    vdst[W] = vTl + c*8;
  }

  f32x4 acc[3];
  #pragma unroll
  for (int j = 0; j < 3; ++j) acc[j] = (f32x4){0.f, 0.f, 0.f, 0.f};
  float m_i = -1e30f, l_i = 0.f;
  const int r_s = t >> 4;        // softmax row (16 lanes/row)
  const int c4  = (t & 15) * 4;  // softmax col base

  // c-constant prefetch (3 loads/wave, uniform)
  float cP[3];
  #pragma unroll
  for (int s = 0; s < 3; ++s) {
    if (isS1T[s]) cP[s] = c1g[h*(BT*TT) + b*TT + 0 + colT[s]];
    else {
      const int mb = 0 - q0 + 1504;
      cP[s] = c2g[(size_t)h*(2*TT - 1) + mb + (colT[s] < 95 ? colT[s] : 94)];
    }
  }
  // prologue staging: kr(3) then v(3)
  #pragma unroll
  for (int W = 0; W < 3; ++W) { gload_lds16(sp[W], sd[W]); sp[W] += sstep; }
  #pragma unroll
  for (int W = 0; W < 3; ++W) { gload_lds16(vsrc[W], vdst[W]); vsrc[W] += 64; }

  for (int it = 0; it < 24; ++it) {
    // ==== phase A: c+kr retired (vmcnt(3) keeps the 3 vT flying) ====
    asm volatile("s_waitcnt vmcnt(3)" ::: "memory");
    __builtin_amdgcn_s_barrier();
    #pragma unroll
    for (int s = 0; s < 3; ++s) {
      if (validT[s]) {
        const int rt = rtT[s], col = colT[s];
        const bf16x8 a0 = rt ? af10 : af00;
        const bf16x8 a1 = rt ? af11 : af01;
        const ushort* base = isS1T[s] ? ktL : rkbL;
        bf16x8 b0 = *(const bf16x8*)&base[col*64 + ((lk8 ^ (col & 7)) << 3)];
        bf16x8 b1 = *(const bf16x8*)&base[col*64 + (((lk8 + 4) ^ (col & 7)) << 3)];
        f32x4 c0 = (f32x4){0.f, 0.f, 0.f, 0.f};
        c0 = mfma_bf(a0, b0, c0);
        c0 = mfma_bf(a1, b1, c0);
        if (isS1T[s]) {
          #pragma unroll
          for (int r = 0; r < 4; ++r) S1[rt*16 + lk8*4 + r][col] = c0[r] + cP[s];
        } else {
          // shift-on-write: S2s[row][j], j = col + row - 31 (one writer per (row,j))
          #pragma unroll
          for (int r = 0; r < 4; ++r) {
            const int row = rt*16 + lk8*4 + r;
            const int j = col + row - 31;
            if (j >= 0 && j < 64) S2s[row][j] = c0[r] + cP[s];
          }
        }
      }
    }
    asm volatile("s_waitcnt lgkmcnt(0)" ::: "memory");
    __builtin_amdgcn_s_barrier();

    // ==== phase B: prefetch c+kr for it+1; softmax; retire vT ====
    if (it < 23) {
      const int kt0n = (it + 1) << 6;
      #pragma unroll
      for (int s = 0; s < 3; ++s) {
        if (isS1T[s]) cP[s] = c1g[h*(BT*TT) + b*TT + kt0n + colT[s]];
        else {
          const int mbn = kt0n - q0 + 1504;
          cP[s] = c2g[(size_t)h*(2*TT - 1) + mbn + (colT[s] < 95 ? colT[s] : 94)];
        }
      }
      #pragma unroll
      for (int W = 0; W < 3; ++W) { gload_lds16(sp[W], sd[W]); sp[W] += sstep; }
    }
    {
      const float4 s1v = *(const float4*)&S1[r_s][c4];
      const float4 s2v = *(const float4*)&S2s[r_s][c4];
      float sv[4] = {s1v.x + s2v.x, s1v.y + s2v.y, s1v.z + s2v.z, s1v.w + s2v.w};
      float lm = fmaxf(fmaxf(sv[0], sv[1]), fmaxf(sv[2], sv[3]));
      #pragma unroll
      for (int sft = 1; sft < 16; sft <<= 1) lm = fmaxf(lm, __shfl_xor(lm, sft, 64));
      const bool defer = (lm <= m_i + 8.0f);
      const float m_new = defer ? m_i : fmaxf(m_i, lm);
      const float corr  = defer ? 1.0f : exp2f(m_i - m_new);
      const float p0 = exp2f(sv[0] - m_new), p1 = exp2f(sv[1] - m_new);
      const float p2 = exp2f(sv[2] - m_new), p3 = exp2f(sv[3] - m_new);
      uint2 pw;
      pw.x = (uint)f2bf(p0) | ((uint)f2bf(p1) << 16);
      pw.y = (uint)f2bf(p2) | ((uint)f2bf(p3) << 16);
      *(uint2*)&Pl[r_s][c4] = pw;
      float ls = (p0 + p1) + (p2 + p3);
      #pragma unroll
      for (int sft = 1; sft < 16; sft <<= 1) ls += __shfl_xor(ls, sft, 64);
      l_i = l_i * corr + ls;
      m_i = m_new;
      if ((t & 15) == 0) corrl[r_s] = corr;
    }
    if (it < 23) { asm volatile("s_waitcnt vmcnt(6)" ::: "memory"); }  // retire vT; keep c(3)+kr(3)
    else         { asm volatile("s_waitcnt vmcnt(0)" ::: "memory"); }
    asm volatile("s_waitcnt lgkmcnt(0)" ::: "memory");
    __builtin_amdgcn_s_barrier();

    // ==== phase C: PV (reads -> regs, barrier, issue next vT, MFMA) ====
    {
      const int rtO = wv >> 2, vb0 = (wv & 3) * 3;
      bf16x8 pa0 = *(const bf16x8*)&Pl[rtO*16 + lrow][lk8*8];
      bf16x8 pa1 = *(const bf16x8*)&Pl[rtO*16 + lrow][32 + lk8*8];
      bf16x8 bv[3][2];
      #pragma unroll
      for (int cc = 0; cc < 3; ++cc) {
        const int rv = (vb0 + cc)*16 + lrow;
        bv[cc][0] = *(const bf16x8*)&vTl[rv*64 + ((lk8 ^ (rv & 7)) << 3)];
        bv[cc][1] = *(const bf16x8*)&vTl[rv*64 + (((lk8 + 4) ^ (rv & 7)) << 3)];
      }
      float cr[4];
      #pragma unroll
      for (int r = 0; r < 4; ++r) cr[r] = corrl[rtO*16 + lk8*4 + r];
      asm volatile("s_waitcnt lgkmcnt(0)" ::: "memory");
      __builtin_amdgcn_s_barrier();
      if (it < 23) {
        #pragma unroll
        for (int W = 0; W < 3; ++W) { gload_lds16(vsrc[W], vdst[W]); vsrc[W] += 64; }
      }
      bool need = (cr[0] != 1.f) | (cr[1] != 1.f) | (cr[2] != 1.f) | (cr[3] != 1.f);
      if (__any(need ? 1 : 0)) {
        #pragma unroll
        for (int cc = 0; cc < 3; ++cc)
          #pragma unroll
          for (int r = 0; r < 4; ++r) acc[cc][r] *= cr[r];
      }
      #pragma unroll
      for (int cc = 0; cc < 3; ++cc) {
        acc[cc] = mfma_bf(pa0, bv[cc][0], acc[cc]);
        acc[cc] = mfma_bf(pa1, bv[cc][1], acc[cc]);
      }
    }
  }
  if ((t & 15) == 0) linv[r_s] = 1.0f / l_i;
  __syncthreads();
  {
    const int rtO = wv >> 2, vb0 = (wv & 3) * 3;
    #pragma unroll
    for (int cc = 0; cc < 3; ++cc) {
      const int colg = (vb0 + cc)*16 + lrow;
      #pragma unroll
      for (int r = 0; r < 4; ++r) {
        const int rowg = rtO*16 + lk8*4 + r;
        aout[((size_t)(b*TT) + q0 + rowg) * HV + h*VD + colg] = f2bf(acc[cc][r] * linv[rowg]);
      }
    }
  }
}

extern "C" void kernel_launch(void* const* d_in, const int* in_sizes, int n_in,
                              void* d_out, int out_size, void* d_ws, size_t ws_size,
                              hipStream_t stream)
{
  const float* X   = (const float*)d_in[0];
  const float* Wq  = (const float*)d_in[1];
  const float* Wk  = (const float*)d_in[2];
  const float* Wv  = (const float*)d_in[3];
  const float* Wrk = (const float*)d_in[4];
  const float* We  = (const float*)d_in[5];
  const float* be  = (const float*)d_in[6];
  const float* rwb = (const float*)d_in[7];
  const float* rrb = (const float*)d_in[8];
  float* out = (float*)d_out;

  char* ws = (char*)d_ws;
  ushort* Xb    = (ushort*)ws;                       ws += (size_t)3072*1536*2;
  ushort* Wqkvt = (ushort*)ws;                       ws += (size_t)2560*1536*2;
  ushort* Wet   = (ushort*)ws;                       ws += (size_t)1536*1536*2;
  float*  S1b   = (float*)ws;                        ws += (size_t)97*512*4;
  float*  S2b   = (float*)ws;                        ws += (size_t)97*512*4;
  ushort* qkvb  = (ushort*)ws;                       ws += (size_t)3072*2560*2;
  ushort* vTgb  = (ushort*)ws;                       ws += (size_t)1536*3072*2;
  ushort* rkb   = (ushort*)ws;                       ws += (size_t)3071*512*2;
  float*  c1g   = (float*)ws;                        ws += (size_t)8*3072*4;
  float*  c2g   = (float*)ws;                        ws += (size_t)8*3071*4;
  ushort* ao    = (ushort*)ws;                       // 3072*1536*2

  dim3 blk(256);
  cast_bf16<<<2048, blk, 0, stream>>>(X, Xb, (3072*1536)/4);
  tcast<<<dim3(512/32, 1536/32),  dim3(32,8), 0, stream>>>(Wq, Wqkvt,                      1536, 512,  0.125f*LOG2E);
  tcast<<<dim3(512/32, 1536/32),  dim3(32,8), 0, stream>>>(Wk, Wqkvt + (size_t)512*1536,   1536, 512,  1.0f);
  tcast<<<dim3(1536/32, 1536/32), dim3(32,8), 0, stream>>>(Wv, Wqkvt + (size_t)1024*1536,  1536, 1536, 1.0f);
  tcast<<<dim3(1536/32, 1536/32), dim3(32,8), 0, stream>>>(We, Wet, 1536, 1536, 1.0f);
  wrk_suffix<<<2, blk, 0, stream>>>(Wrk, S1b, S2b);
  relk_fill<<<dim3(2*TT - 1), blk, 0, stream>>>(S1b, S2b, rrb, rkb, c2g);
  gemm_bf16<false, ushort><<<dim3(20, 24), blk, 0, stream>>>(Xb, Wqkvt, nullptr, qkvb, 3072, QKVP, 1536);
  vtrans<<<dim3(1536/32, 3072/32), dim3(32,8), 0, stream>>>(qkvb, vTgb);
  c1_kernel<<<96, blk, 0, stream>>>(qkvb, rwb, c1g);
  attn_mfma<<<dim3(BT*HB*(TT/32)), dim3(512), 0, stream>>>(qkvb, vTgb, rkb, c1g, c2g, ao);
  gemm_bf16<true, float><<<dim3(12, 24), blk, 0, stream>>>(ao, Wet, be, out, 3072, 1536, 1536);
}

// Round 14
// 203.357 us; speedup vs baseline: 1.3055x; 1.3055x over previous
//
#include <hip/hip_runtime.h>
#include <math.h>

#define HB 8
#define KD 64
#define VD 192
#define BT 2
#define TT 1536
#define CC 1536
#define HK (HB*KD)   // 512
#define HV (HB*VD)   // 1536
#define QKVP 2560    // fused qkv row pitch: q[0:512) k[512:1024) v[1024:2560)
#define LOG2E 1.44269504088896340736f

typedef float f32x4 __attribute__((ext_vector_type(4)));
typedef __bf16 bf16x8 __attribute__((ext_vector_type(8)));

static __device__ __forceinline__ ushort f2bf(float f) {
  union { float f; uint u; } v; v.f = f;
  uint r = (v.u + 0x7FFFu + ((v.u >> 16) & 1u)) >> 16;  // RNE
  return (ushort)r;
}
static __device__ __forceinline__ float bf2f(ushort u) {
  union { uint u; float f; } v; v.u = ((uint)u) << 16; return v.f;
}

static __device__ __forceinline__ f32x4 mfma_bf(bf16x8 a, bf16x8 b, f32x4 c) {
  return __builtin_amdgcn_mfma_f32_16x16x32_bf16(a, b, c, 0, 0, 0);
}

static __device__ __forceinline__ void gload_lds16(const ushort* g, ushort* l) {
  __builtin_amdgcn_global_load_lds(
      (const __attribute__((address_space(1))) unsigned int*)g,
      (__attribute__((address_space(3))) unsigned int*)l, 16, 0, 0);
}

__device__ __forceinline__ void storeC(float* p, float v) { *p = v; }
__device__ __forceinline__ void storeC(ushort* p, float v) { *p = f2bf(v); }

// ---------------- fused prep: cast X->bf16 | Wrk suffix sums | 4x transpose+cast ----------------
// blocks [0,2048): cast; [2048,2050): wrk_suffix; [2050,8194): tcast tiles
__global__ __launch_bounds__(256) void prep_kernel(
    const float* __restrict__ X,  const float* __restrict__ Wq,
    const float* __restrict__ Wk, const float* __restrict__ Wv,
    const float* __restrict__ We, const float* __restrict__ Wrk,
    ushort* __restrict__ Xb, ushort* __restrict__ Wqkvt, ushort* __restrict__ Wet,
    float* __restrict__ S1b, float* __restrict__ S2b)
{
  const int blk = blockIdx.x;
  const int t = threadIdx.x;
  if (blk < 2048) {
    const int n4 = (3072*1536)/4;
    for (int i = blk*256 + t; i < n4; i += 2048*256) {
      float4 v = ((const float4*)X)[i];
      ushort4 o; o.x = f2bf(v.x); o.y = f2bf(v.y); o.z = f2bf(v.z); o.w = f2bf(v.w);
      ((ushort4*)Xb)[i] = o;
    }
  } else if (blk < 2050) {
    const int c = (blk - 2048)*256 + t;   // 0..511
    float a1 = 0.f, a2 = 0.f;
    S1b[96*HK + c] = 0.f; S2b[96*HK + c] = 0.f;
    for (int i = 95; i >= 0; --i) {
      a1 += Wrk[i*HK + c];
      a2 += Wrk[(96 + i)*HK + c];
      S1b[i*HK + c] = a1; S2b[i*HK + c] = a2;
    }
  } else {
    int u = blk - 2050;
    const float* in; ushort* out; int R, C; float scale; int bxi, byi;
    if (u < 768)       { in = Wq; out = Wqkvt;                     R = 1536; C = 512;  scale = 0.125f*LOG2E; bxi = u % 16; byi = u / 16; }
    else if (u < 1536) { u -= 768;  in = Wk; out = Wqkvt + (size_t)512*1536;  R = 1536; C = 512;  scale = 1.0f; bxi = u % 16; byi = u / 16; }
    else if (u < 3840) { u -= 1536; in = Wv; out = Wqkvt + (size_t)1024*1536; R = 1536; C = 1536; scale = 1.0f; bxi = u % 48; byi = u / 48; }
    else               { u -= 3840; in = We; out = Wet;            R = 1536; C = 1536; scale = 1.0f; bxi = u % 48; byi = u / 48; }
    const int bx = bxi*32, by = byi*32;
    const int tx = t & 31, ty = t >> 5;   // (32,8)
    __shared__ float tile[32][33];
    #pragma unroll
    for (int i = 0; i < 4; ++i)
      tile[ty + i*8][tx] = in[(size_t)(by + ty + i*8)*C + bx + tx];
    __syncthreads();
    #pragma unroll
    for (int i = 0; i < 4; ++i)
      out[(size_t)(bx + ty + i*8)*R + by + tx] = f2bf(tile[tx][ty + i*8] * scale);
  }
}

// ---------------- bf16 MFMA GEMM: C[M,N] = A[M,Kd] @ Bt[N,Kd]^T (+bias) ----------------
template<bool WITH_BIAS, typename OutT>
__global__ __launch_bounds__(256) void gemm_bf16(
    const ushort* __restrict__ A, const ushort* __restrict__ Bt,
    const float* __restrict__ bias, OutT* __restrict__ C,
    int M, int N, int Kd)
{
  __shared__ __align__(16) ushort As[128*64];
  __shared__ __align__(16) ushort Bs[128*64];
  const int t = threadIdx.x;
  const int w = t >> 6, lane = t & 63;
  const int lrow = lane & 15, lk8 = lane >> 4;
  const int row0 = blockIdx.y * 128, col0 = blockIdx.x * 128;
  const int wr = (w >> 1) * 64, wc = (w & 1) * 64;

  f32x4 acc[4][4];
  #pragma unroll
  for (int m = 0; m < 4; ++m)
    #pragma unroll
    for (int n = 0; n < 4; ++n) acc[m][n] = (f32x4){0.f,0.f,0.f,0.f};

  for (int k0 = 0; k0 < Kd; k0 += 64) {
    __syncthreads();
    #pragma unroll
    for (int j = 0; j < 4; ++j) {
      const int c = (w*4 + j)*64 + lane;
      const int r = c >> 3, cp = c & 7;
      const int sc = cp ^ (r & 7);
      gload_lds16(A  + (size_t)(row0 + r)*Kd + k0 + sc*8, As + c*8);
      gload_lds16(Bt + (size_t)(col0 + r)*Kd + k0 + sc*8, Bs + c*8);
    }
    __syncthreads();
    bf16x8 af[4][2], bfv[4][2];
    #pragma unroll
    for (int m = 0; m < 4; ++m) {
      const int r = wr + m*16 + lrow;
      #pragma unroll
      for (int kh = 0; kh < 2; ++kh) {
        const int k8 = lk8 + kh*4;
        af[m][kh] = *(const bf16x8*)&As[r*64 + ((k8 ^ (r & 7)) << 3)];
      }
    }
    #pragma unroll
    for (int n = 0; n < 4; ++n) {
      const int r = wc + n*16 + lrow;
      #pragma unroll
      for (int kh = 0; kh < 2; ++kh) {
        const int k8 = lk8 + kh*4;
        bfv[n][kh] = *(const bf16x8*)&Bs[r*64 + ((k8 ^ (r & 7)) << 3)];
      }
    }
    #pragma unroll
    for (int m = 0; m < 4; ++m)
      #pragma unroll
      for (int n = 0; n < 4; ++n) {
        acc[m][n] = mfma_bf(af[m][0], bfv[n][0], acc[m][n]);
        acc[m][n] = mfma_bf(af[m][1], bfv[n][1], acc[m][n]);
      }
  }
  #pragma unroll
  for (int m = 0; m < 4; ++m)
    #pragma unroll
    for (int n = 0; n < 4; ++n) {
      const int cg = col0 + wc + n*16 + lrow;
      const float bb = WITH_BIAS ? bias[cg] : 0.f;
      #pragma unroll
      for (int r = 0; r < 4; ++r) {
        const int rg = row0 + wr + m*16 + lk8*4 + r;
        storeC(&C[(size_t)rg*N + cg], acc[m][n][r] + bb);
      }
    }
}

// ---------------- rk[m][c] bf16 + c2[h][m] = (rrb_h . rk[m]) * log2e ----------------
__global__ __launch_bounds__(256) void relk_fill(
    const float* __restrict__ S1, const float* __restrict__ S2,
    const float* __restrict__ rrb, ushort* __restrict__ rk, float* __restrict__ c2g)
{
  __shared__ float cw[96];
  __shared__ float red[512];
  __shared__ int i0s;
  const int t = threadIdx.x;
  const int m = blockIdx.x;            // 0 .. 2T-2
  if (t < 96) {
    double pr = exp(log((double)(TT + 1)) / 96.0);
    float prf = (float)pr;
    cw[t] = (float)pow((double)prf, (double)(t + 1)) - 1.0f;
  }
  __syncthreads();
  const int d = m - (TT - 1);
  const float ad = fabsf((float)d);
  if (t == 0) {
    int i0 = 96;
    for (int i = 0; i < 96; ++i) if (cw[i] > ad) { i0 = i; break; }
    i0s = i0;
  }
  __syncthreads();
  const float sg = (d > 0) ? 1.f : (d < 0 ? -1.f : 0.f);
  const int i0 = i0s;
  for (int c = t; c < HK; c += 256) {
    const float val = S1[i0*HK + c] + sg * S2[i0*HK + c];
    const ushort vb = f2bf(val);
    rk[(size_t)m * HK + c] = vb;
    red[c] = bf2f(vb) * rrb[c];
  }
  __syncthreads();
  if (t < 8) {
    float s = 0.f;
    #pragma unroll 16
    for (int i = 0; i < 64; ++i) s += red[t*64 + i];
    c2g[(size_t)t*(2*TT - 1) + m] = s * LOG2E;
  }
}

// ---------------- fused: V transpose tiles | c1[h][row] = (rwb_h . k[row]) * log2e ----------------
// blocks [0,4608): vtrans tiles (48 vd-tiles x 96 key-tiles); [4608,4704): c1
__global__ __launch_bounds__(256) void vtrans_c1(
    const ushort* __restrict__ qkv, const float* __restrict__ rwb,
    ushort* __restrict__ vTg, float* __restrict__ c1g)
{
  const int blk = blockIdx.x;
  const int t = threadIdx.x;
  if (blk < 4608) {
    const int bx = (blk % 48) * 32;   // vd base
    const int by = (blk / 48) * 32;   // key base
    const int tx = t & 31, ty = t >> 5;
    __shared__ ushort tile[32][33];
    #pragma unroll
    for (int i = 0; i < 4; ++i)
      tile[ty + i*8][tx] = qkv[(size_t)(by + ty + i*8)*QKVP + 1024 + bx + tx];
    __syncthreads();
    #pragma unroll
    for (int i = 0; i < 4; ++i)
      vTg[(size_t)(bx + ty + i*8)*(BT*TT) + by + tx] = tile[tx][ty + i*8];
  } else {
    const int idx = (blk - 4608)*256 + t;  // 3072*8
    const int h = idx & 7, row = idx >> 3;
    const ushort* kr = &qkv[(size_t)row*QKVP + 512 + h*KD];
    float s = 0.f;
    #pragma unroll 16
    for (int c = 0; c < 64; ++c) s += bf2f(kr[c]) * rwb[h*KD + c];
    c1g[h*(BT*TT) + row] = s * LOG2E;
  }
}

// ---------------- fused relative attention: KBLK=64, counted-vmcnt pipeline, XCD-swizzled grid ----------------
// bid = qt*16 + b*8 + h  =>  bid % 8 == h: all 96 blocks of head h land on XCD h
__global__ __launch_bounds__(256, 2) void attn_mfma(
    const ushort* __restrict__ qkv, const ushort* __restrict__ vTg,
    const ushort* __restrict__ rk,
    const float* __restrict__ c1g, const float* __restrict__ c2g,
    ushort* __restrict__ aout)
{
  __shared__ __align__(16) ushort ktL[64*64];    // k tile (8 KB)
  __shared__ __align__(16) ushort rkbL[96*64];   // rk band (12 KB), row 95 zero
  __shared__ __align__(16) ushort vTl[192*64];   // vT tile (24 KB)
  __shared__ __align__(16) ushort Pl[32][72];    // probabilities bf16 (4.5 KB)
  __shared__ __align__(16) float S1[32][68];     // content logits (8.5 KB)
  __shared__ __align__(16) float S2[32][98];     // rel logits, 95-wide band (12.25 KB)
  __shared__ float corrl[32], linv[32];

  const int t = threadIdx.x;
  const int wv = t >> 6, lane = t & 63;
  const int lrow = lane & 15, lk8 = lane >> 4;
  const int bid = blockIdx.x;
  const int qt = bid >> 4;          // XCD swizzle: qt in high bits
  const int h  = bid & 7;
  const int b  = (bid >> 3) & 1;
  const int q0 = qt * 32;

  bf16x8 af00, af01, af10, af11;
  {
    const ushort* qbase = &qkv[((size_t)(b*TT) + q0 + lrow)*QKVP + h*KD];
    af00 = *(const bf16x8*)&qbase[lk8*8];
    af01 = *(const bf16x8*)&qbase[32 + lk8*8];
    af10 = *(const bf16x8*)&qbase[16*QKVP + lk8*8];
    af11 = *(const bf16x8*)&qbase[16*QKVP + 32 + lk8*8];
  }

  if (t < 32) ((uint*)rkbL)[95*32 + t] = 0;   // zero pad row 95

  const ushort* ksrc[2]; ushort* kdst[2];
  #pragma unroll
  for (int W = 0; W < 2; ++W) {
    const int c = W*256 + t;
    const int r = c >> 3, cp = c & 7;
    ksrc[W] = qkv + (size_t)(b*TT + r)*QKVP + 512 + h*KD + (cp ^ (r & 7))*8;
    kdst[W] = ktL + c*8;
  }
  const ushort* rsrc[3]; ushort* rdst[3];
  #pragma unroll
  for (int W = 0; W < 3; ++W) {
    const int c = W*256 + t;
    const int r = c >> 3, cp = c & 7;
    rsrc[W] = rk + (size_t)(1504 - q0 + r)*HK + h*KD + (cp ^ (r & 7))*8;
    rdst[W] = rkbL + c*8;
  }
  const bool rval = t < 248;
  const ushort* vsrc[6]; ushort* vdst[6];
  #pragma unroll
  for (int W = 0; W < 6; ++W) {
    const int c = W*256 + t;
    const int vd = c >> 3, cpk = c & 7;
    vsrc[W] = vTg + (size_t)(h*VD + vd)*(BT*TT) + b*TT + (cpk ^ (vd & 7))*8;
    vdst[W] = vTl + c*8;
  }

  int jk_[2], rt1_[2], j2_[3], rt2_[3];
  #pragma unroll
  for (int s = 0; s < 2; ++s) {
    const int idx = wv*2 + s;
    rt1_[s] = idx >> 2; jk_[s] = (idx & 3)*16 + lrow;
  }
  #pragma unroll
  for (int s = 0; s < 3; ++s) {
    const int idx = wv*3 + s;
    rt2_[s] = (idx >= 6) ? 1 : 0; j2_[s] = (idx - 6*rt2_[s])*16 + lrow;
  }

  f32x4 acc[2][3];
  #pragma unroll
  for (int i = 0; i < 2; ++i)
    #pragma unroll
    for (int j = 0; j < 3; ++j) acc[i][j] = (f32x4){0.f, 0.f, 0.f, 0.f};
  float m_i = -1e30f, l_i = 0.f;
  const int r_s = t >> 3;
  const int vsl = t & 7;

  float c1p[2], c2p[3];
  {
    const int mb0 = -q0 + 1504;
    #pragma unroll
    for (int s = 0; s < 2; ++s) c1p[s] = c1g[h*(BT*TT) + b*TT + jk_[s]];
    #pragma unroll
    for (int s = 0; s < 3; ++s) {
      const float v = c2g[(size_t)h*(2*TT - 1) + mb0 + (j2_[s] < 95 ? j2_[s] : 94)];
      c2p[s] = (j2_[s] < 95) ? v : 0.f;
    }
  }
  #pragma unroll
  for (int W = 0; W < 2; ++W) { gload_lds16(ksrc[W], kdst[W]); ksrc[W] += 64*QKVP; }
  gload_lds16(rsrc[0], rdst[0]);           rsrc[0] += 64*HK;
  gload_lds16(rsrc[1], rdst[1]);           rsrc[1] += 64*HK;
  if (rval) gload_lds16(rsrc[2], rdst[2]);
  rsrc[2] += 64*HK;
  #pragma unroll
  for (int W = 0; W < 6; ++W) { gload_lds16(vsrc[W], vdst[W]); vsrc[W] += 64; }

  for (int it = 0; it < 24; ++it) {
    // ==== phase A: S-compute (k/rkb + c1c2 retired; vT still flying) ====
    asm volatile("s_waitcnt vmcnt(6)" ::: "memory");
    __builtin_amdgcn_s_barrier();
    #pragma unroll
    for (int s = 0; s < 2; ++s) {
      const int rt = rt1_[s], jk = jk_[s];
      const bf16x8 a0 = rt ? af10 : af00;
      const bf16x8 a1 = rt ? af11 : af01;
      bf16x8 b0 = *(const bf16x8*)&ktL[jk*64 + ((lk8 ^ (jk & 7)) << 3)];
      bf16x8 b1 = *(const bf16x8*)&ktL[jk*64 + (((lk8 + 4) ^ (jk & 7)) << 3)];
      f32x4 c0 = (f32x4){0.f, 0.f, 0.f, 0.f};
      c0 = mfma_bf(a0, b0, c0);
      c0 = mfma_bf(a1, b1, c0);
      #pragma unroll
      for (int r = 0; r < 4; ++r) S1[rt*16 + lk8*4 + r][jk] = c0[r] + c1p[s];
    }
    #pragma unroll
    for (int s = 0; s < 3; ++s) {
      const int rt = rt2_[s], j2 = j2_[s];
      const bf16x8 a0 = rt ? af10 : af00;
      const bf16x8 a1 = rt ? af11 : af01;
      bf16x8 b0 = *(const bf16x8*)&rkbL[j2*64 + ((lk8 ^ (j2 & 7)) << 3)];
      bf16x8 b1 = *(const bf16x8*)&rkbL[j2*64 + (((lk8 + 4) ^ (j2 & 7)) << 3)];
      f32x4 c0 = (f32x4){0.f, 0.f, 0.f, 0.f};
      c0 = mfma_bf(a0, b0, c0);
      c0 = mfma_bf(a1, b1, c0);
      #pragma unroll
      for (int r = 0; r < 4; ++r) S2[rt*16 + lk8*4 + r][j2] = c0[r] + c2p[s];
    }
    asm volatile("s_waitcnt lgkmcnt(0)" ::: "memory");
    __builtin_amdgcn_s_barrier();

    // ==== phase B: issue next k/rkb + c1c2 prefetch; softmax; retire vT ====
    if (it < 23) {
      #pragma unroll
      for (int W = 0; W < 2; ++W) { gload_lds16(ksrc[W], kdst[W]); ksrc[W] += 64*QKVP; }
      gload_lds16(rsrc[0], rdst[0]);           rsrc[0] += 64*HK;
      gload_lds16(rsrc[1], rdst[1]);           rsrc[1] += 64*HK;
      if (rval) gload_lds16(rsrc[2], rdst[2]);
      rsrc[2] += 64*HK;
      const int kt0n = (it + 1) << 6;
      const int mbn = kt0n - q0 + 1504;
      #pragma unroll
      for (int s = 0; s < 2; ++s) c1p[s] = c1g[h*(BT*TT) + b*TT + kt0n + jk_[s]];
      #pragma unroll
      for (int s = 0; s < 3; ++s) {
        const float v = c2g[(size_t)h*(2*TT - 1) + mbn + (j2_[s] < 95 ? j2_[s] : 94)];
        c2p[s] = (j2_[s] < 95) ? v : 0.f;
      }
    }
    {
      float sv[8];
      #pragma unroll
      for (int i = 0; i < 8; ++i) {
        const int j = vsl*8 + i;
        sv[i] = S1[r_s][j] + S2[r_s][j - r_s + 31];
      }
      float lmax = sv[0];
      #pragma unroll
      for (int i = 1; i < 8; ++i) lmax = fmaxf(lmax, sv[i]);
      #pragma unroll
      for (int s = 1; s < 8; s <<= 1) lmax = fmaxf(lmax, __shfl_xor(lmax, s, 64));
      const bool defer = (lmax <= m_i + 8.0f);
      const float m_new = defer ? m_i : fmaxf(m_i, lmax);
      const float corr  = defer ? 1.0f : exp2f(m_i - m_new);
      float p[8];
      float lsum = 0.f;
      #pragma unroll
      for (int i = 0; i < 8; ++i) { p[i] = exp2f(sv[i] - m_new); lsum += p[i]; }
      uint4 pw;
      pw.x = (uint)f2bf(p[0]) | ((uint)f2bf(p[1]) << 16);
      pw.y = (uint)f2bf(p[2]) | ((uint)f2bf(p[3]) << 16);
      pw.z = (uint)f2bf(p[4]) | ((uint)f2bf(p[5]) << 16);
      pw.w = (uint)f2bf(p[6]) | ((uint)f2bf(p[7]) << 16);
      *(uint4*)&Pl[r_s][vsl*8] = pw;
      #pragma unroll
      for (int s = 1; s < 8; s <<= 1) lsum += __shfl_xor(lsum, s, 64);
      l_i = l_i * corr + lsum;
      m_i = m_new;
      if (vsl == 0) corrl[r_s] = corr;
    }
    if (it < 23) { asm volatile("s_waitcnt vmcnt(10)" ::: "memory"); }
    else         { asm volatile("s_waitcnt vmcnt(0)"  ::: "memory"); }
    asm volatile("s_waitcnt lgkmcnt(0)" ::: "memory");
    __builtin_amdgcn_s_barrier();

    // ==== phase C: PV (operands -> regs, barrier, issue next vT, MFMA) ====
    {
      bf16x8 pa[2][2], bv[3][2];
      #pragma unroll
      for (int rt = 0; rt < 2; ++rt) {
        pa[rt][0] = *(const bf16x8*)&Pl[rt*16 + lrow][lk8*8];
        pa[rt][1] = *(const bf16x8*)&Pl[rt*16 + lrow][32 + lk8*8];
      }
      #pragma unroll
      for (int cc = 0; cc < 3; ++cc) {
        const int rv = (3*wv + cc)*16 + lrow;
        bv[cc][0] = *(const bf16x8*)&vTl[rv*64 + ((lk8 ^ (rv & 7)) << 3)];
        bv[cc][1] = *(const bf16x8*)&vTl[rv*64 + (((lk8 + 4) ^ (rv & 7)) << 3)];
      }
      float cr[2][4];
      #pragma unroll
      for (int rt = 0; rt < 2; ++rt)
        #pragma unroll
        for (int r = 0; r < 4; ++r) cr[rt][r] = corrl[rt*16 + lk8*4 + r];
      asm volatile("s_waitcnt lgkmcnt(0)" ::: "memory");
      __builtin_amdgcn_s_barrier();
      if (it < 23) {
        #pragma unroll
        for (int W = 0; W < 6; ++W) { gload_lds16(vsrc[W], vdst[W]); vsrc[W] += 64; }
      }
      bool need = false;
      #pragma unroll
      for (int rt = 0; rt < 2; ++rt)
        #pragma unroll
        for (int r = 0; r < 4; ++r) need |= (cr[rt][r] != 1.0f);
      if (__any(need ? 1 : 0)) {
        #pragma unroll
        for (int rt = 0; rt < 2; ++rt)
          #pragma unroll
          for (int cc = 0; cc < 3; ++cc)
            #pragma unroll
            for (int r = 0; r < 4; ++r) acc[rt][cc][r] *= cr[rt][r];
      }
      #pragma unroll
      for (int rt = 0; rt < 2; ++rt)
        #pragma unroll
        for (int cc = 0; cc < 3; ++cc) {
          acc[rt][cc] = mfma_bf(pa[rt][0], bv[cc][0], acc[rt][cc]);
          acc[rt][cc] = mfma_bf(pa[rt][1], bv[cc][1], acc[rt][cc]);
        }
    }
  }
  if (vsl == 0) linv[r_s] = 1.0f / l_i;
  __syncthreads();
  #pragma unroll
  for (int rt = 0; rt < 2; ++rt) {
    #pragma unroll
    for (int cc = 0; cc < 3; ++cc) {
      const int colg = (3*wv + cc)*16 + lrow;
      #pragma unroll
      for (int r = 0; r < 4; ++r) {
        const int rowg = rt*16 + lk8*4 + r;
        aout[((size_t)(b*TT) + q0 + rowg) * HV + h*VD + colg] = f2bf(acc[rt][cc][r] * linv[rowg]);
      }
    }
  }
}

extern "C" void kernel_launch(void* const* d_in, const int* in_sizes, int n_in,
                              void* d_out, int out_size, void* d_ws, size_t ws_size,
                              hipStream_t stream)
{
  const float* X   = (const float*)d_in[0];
  const float* Wq  = (const float*)d_in[1];
  const float* Wk  = (const float*)d_in[2];
  const float* Wv  = (const float*)d_in[3];
  const float* Wrk = (const float*)d_in[4];
  const float* We  = (const float*)d_in[5];
  const float* be  = (const float*)d_in[6];
  const float* rwb = (const float*)d_in[7];
  const float* rrb = (const float*)d_in[8];
  float* out = (float*)d_out;

  char* ws = (char*)d_ws;
  ushort* Xb    = (ushort*)ws;                       ws += (size_t)3072*1536*2;
  ushort* Wqkvt = (ushort*)ws;                       ws += (size_t)2560*1536*2;
  ushort* Wet   = (ushort*)ws;                       ws += (size_t)1536*1536*2;
  float*  S1b   = (float*)ws;                        ws += (size_t)97*512*4;
  float*  S2b   = (float*)ws;                        ws += (size_t)97*512*4;
  ushort* qkvb  = (ushort*)ws;                       ws += (size_t)3072*2560*2;
  ushort* vTgb  = (ushort*)ws;                       ws += (size_t)1536*3072*2;
  ushort* rkb   = (ushort*)ws;                       ws += (size_t)3071*512*2;
  float*  c1g   = (float*)ws;                        ws += (size_t)8*3072*4;
  float*  c2g   = (float*)ws;                        ws += (size_t)8*3071*4;
  ushort* ao    = (ushort*)ws;                       // 3072*1536*2

  dim3 blk(256);
  prep_kernel<<<dim3(8194), blk, 0, stream>>>(X, Wq, Wk, Wv, We, Wrk, Xb, Wqkvt, Wet, S1b, S2b);
  relk_fill<<<dim3(2*TT - 1), blk, 0, stream>>>(S1b, S2b, rrb, rkb, c2g);
  gemm_bf16<false, ushort><<<dim3(20, 24), blk, 0, stream>>>(Xb, Wqkvt, nullptr, qkvb, 3072, QKVP, 1536);
  vtrans_c1<<<dim3(4704), blk, 0, stream>>>(qkvb, rwb, vTgb, c1g);
  attn_mfma<<<dim3(BT*HB*(TT/32)), blk, 0, stream>>>(qkvb, vTgb, rkb, c1g, c2g, ao);
  gemm_bf16<true, float><<<dim3(12, 24), blk, 0, stream>>>(ao, Wet, be, out, 3072, 1536, 1536);
}

// Round 15
// 200.743 us; speedup vs baseline: 1.3225x; 1.0130x over previous
//
#include <hip/hip_runtime.h>
#include <math.h>

#define HB 8
#define KD 64
#define VD 192
#define BT 2
#define TT 1536
#define CC 1536
#define HK (HB*KD)   // 512
#define HV (HB*VD)   // 1536
#define QKVP 2560    // fused qkv row pitch: q[0:512) k[512:1024) v[1024:2560)
#define LOG2E 1.44269504088896340736f

typedef float f32x4 __attribute__((ext_vector_type(4)));
typedef __bf16 bf16x8 __attribute__((ext_vector_type(8)));

static __device__ __forceinline__ ushort f2bf(float f) {
  union { float f; uint u; } v; v.f = f;
  uint r = (v.u + 0x7FFFu + ((v.u >> 16) & 1u)) >> 16;  // RNE
  return (ushort)r;
}
static __device__ __forceinline__ float bf2f(ushort u) {
  union { uint u; float f; } v; v.u = ((uint)u) << 16; return v.f;
}

static __device__ __forceinline__ f32x4 mfma_bf(bf16x8 a, bf16x8 b, f32x4 c) {
  return __builtin_amdgcn_mfma_f32_16x16x32_bf16(a, b, c, 0, 0, 0);
}

static __device__ __forceinline__ void gload_lds16(const ushort* g, ushort* l) {
  __builtin_amdgcn_global_load_lds(
      (const __attribute__((address_space(1))) unsigned int*)g,
      (__attribute__((address_space(3))) unsigned int*)l, 16, 0, 0);
}

__device__ __forceinline__ void storeC(float* p, float v) { *p = v; }
__device__ __forceinline__ void storeC(ushort* p, float v) { *p = f2bf(v); }

// ---------------- fused prep: cast X->bf16 | Wrk suffix sums | 4x transpose+cast ----------------
// blocks [0,2048): cast; [2048,2050): wrk_suffix; [2050,8194): tcast tiles
__global__ __launch_bounds__(256) void prep_kernel(
    const float* __restrict__ X,  const float* __restrict__ Wq,
    const float* __restrict__ Wk, const float* __restrict__ Wv,
    const float* __restrict__ We, const float* __restrict__ Wrk,
    ushort* __restrict__ Xb, ushort* __restrict__ Wqkvt, ushort* __restrict__ Wet,
    float* __restrict__ S1b, float* __restrict__ S2b)
{
  const int blk = blockIdx.x;
  const int t = threadIdx.x;
  if (blk < 2048) {
    const int n4 = (3072*1536)/4;
    for (int i = blk*256 + t; i < n4; i += 2048*256) {
      float4 v = ((const float4*)X)[i];
      ushort4 o; o.x = f2bf(v.x); o.y = f2bf(v.y); o.z = f2bf(v.z); o.w = f2bf(v.w);
      ((ushort4*)Xb)[i] = o;
    }
  } else if (blk < 2050) {
    const int c = (blk - 2048)*256 + t;   // 0..511
    float a1 = 0.f, a2 = 0.f;
    S1b[96*HK + c] = 0.f; S2b[96*HK + c] = 0.f;
    for (int i = 95; i >= 0; --i) {
      a1 += Wrk[i*HK + c];
      a2 += Wrk[(96 + i)*HK + c];
      S1b[i*HK + c] = a1; S2b[i*HK + c] = a2;
    }
  } else {
    int u = blk - 2050;
    const float* in; ushort* out; int R, C; float scale; int bxi, byi;
    if (u < 768)       { in = Wq; out = Wqkvt;                     R = 1536; C = 512;  scale = 0.125f*LOG2E; bxi = u % 16; byi = u / 16; }
    else if (u < 1536) { u -= 768;  in = Wk; out = Wqkvt + (size_t)512*1536;  R = 1536; C = 512;  scale = 1.0f; bxi = u % 16; byi = u / 16; }
    else if (u < 3840) { u -= 1536; in = Wv; out = Wqkvt + (size_t)1024*1536; R = 1536; C = 1536; scale = 1.0f; bxi = u % 48; byi = u / 48; }
    else               { u -= 3840; in = We; out = Wet;            R = 1536; C = 1536; scale = 1.0f; bxi = u % 48; byi = u / 48; }
    const int bx = bxi*32, by = byi*32;
    const int tx = t & 31, ty = t >> 5;   // (32,8)
    __shared__ float tile[32][33];
    #pragma unroll
    for (int i = 0; i < 4; ++i)
      tile[ty + i*8][tx] = in[(size_t)(by + ty + i*8)*C + bx + tx];
    __syncthreads();
    #pragma unroll
    for (int i = 0; i < 4; ++i)
      out[(size_t)(bx + ty + i*8)*R + by + tx] = f2bf(tile[tx][ty + i*8] * scale);
  }
}

// ---------------- bf16 MFMA GEMM: C[M,N] = A[M,Kd] @ Bt[N,Kd]^T (+bias) ----------------
// 1D grid with XCD-aware chunked swizzle (requires gridDim.x % 8 == 0):
// XCD i gets a contiguous run of tiles -> A-panels become single-XCD L2-resident.
template<bool WITH_BIAS, typename OutT>
__global__ __launch_bounds__(256) void gemm_bf16(
    const ushort* __restrict__ A, const ushort* __restrict__ Bt,
    const float* __restrict__ bias, OutT* __restrict__ C,
    int M, int N, int Kd)
{
  __shared__ __align__(16) ushort As[128*64];
  __shared__ __align__(16) ushort Bs[128*64];
  const int t = threadIdx.x;
  const int w = t >> 6, lane = t & 63;
  const int lrow = lane & 15, lk8 = lane >> 4;
  const int nwg = gridDim.x;
  const int qchunk = nwg >> 3;
  const int swz = (blockIdx.x & 7) * qchunk + (blockIdx.x >> 3);
  const int NX = N >> 7;
  const int row0 = (swz / NX) * 128, col0 = (swz % NX) * 128;
  const int wr = (w >> 1) * 64, wc = (w & 1) * 64;

  f32x4 acc[4][4];
  #pragma unroll
  for (int m = 0; m < 4; ++m)
    #pragma unroll
    for (int n = 0; n < 4; ++n) acc[m][n] = (f32x4){0.f,0.f,0.f,0.f};

  for (int k0 = 0; k0 < Kd; k0 += 64) {
    __syncthreads();
    #pragma unroll
    for (int j = 0; j < 4; ++j) {
      const int c = (w*4 + j)*64 + lane;
      const int r = c >> 3, cp = c & 7;
      const int sc = cp ^ (r & 7);
      gload_lds16(A  + (size_t)(row0 + r)*Kd + k0 + sc*8, As + c*8);
      gload_lds16(Bt + (size_t)(col0 + r)*Kd + k0 + sc*8, Bs + c*8);
    }
    __syncthreads();
    bf16x8 af[4][2], bfv[4][2];
    #pragma unroll
    for (int m = 0; m < 4; ++m) {
      const int r = wr + m*16 + lrow;
      #pragma unroll
      for (int kh = 0; kh < 2; ++kh) {
        const int k8 = lk8 + kh*4;
        af[m][kh] = *(const bf16x8*)&As[r*64 + ((k8 ^ (r & 7)) << 3)];
      }
    }
    #pragma unroll
    for (int n = 0; n < 4; ++n) {
      const int r = wc + n*16 + lrow;
      #pragma unroll
      for (int kh = 0; kh < 2; ++kh) {
        const int k8 = lk8 + kh*4;
        bfv[n][kh] = *(const bf16x8*)&Bs[r*64 + ((k8 ^ (r & 7)) << 3)];
      }
    }
    #pragma unroll
    for (int m = 0; m < 4; ++m)
      #pragma unroll
      for (int n = 0; n < 4; ++n) {
        acc[m][n] = mfma_bf(af[m][0], bfv[n][0], acc[m][n]);
        acc[m][n] = mfma_bf(af[m][1], bfv[n][1], acc[m][n]);
      }
  }
  #pragma unroll
  for (int m = 0; m < 4; ++m)
    #pragma unroll
    for (int n = 0; n < 4; ++n) {
      const int cg = col0 + wc + n*16 + lrow;
      const float bb = WITH_BIAS ? bias[cg] : 0.f;
      #pragma unroll
      for (int r = 0; r < 4; ++r) {
        const int rg = row0 + wr + m*16 + lk8*4 + r;
        storeC(&C[(size_t)rg*N + cg], acc[m][n][r] + bb);
      }
    }
}

// ---------------- rk[m][c] bf16 + c2[h][m] = (rrb_h . rk[m]) * log2e ----------------
__global__ __launch_bounds__(256) void relk_fill(
    const float* __restrict__ S1, const float* __restrict__ S2,
    const float* __restrict__ rrb, ushort* __restrict__ rk, float* __restrict__ c2g)
{
  __shared__ float cw[96];
  __shared__ float red[512];
  __shared__ int i0s;
  const int t = threadIdx.x;
  const int m = blockIdx.x;            // 0 .. 2T-2
  if (t < 96) {
    double pr = exp(log((double)(TT + 1)) / 96.0);
    float prf = (float)pr;
    cw[t] = (float)pow((double)prf, (double)(t + 1)) - 1.0f;
  }
  __syncthreads();
  const int d = m - (TT - 1);
  const float ad = fabsf((float)d);
  if (t == 0) {
    int i0 = 96;
    for (int i = 0; i < 96; ++i) if (cw[i] > ad) { i0 = i; break; }
    i0s = i0;
  }
  __syncthreads();
  const float sg = (d > 0) ? 1.f : (d < 0 ? -1.f : 0.f);
  const int i0 = i0s;
  for (int c = t; c < HK; c += 256) {
    const float val = S1[i0*HK + c] + sg * S2[i0*HK + c];
    const ushort vb = f2bf(val);
    rk[(size_t)m * HK + c] = vb;
    red[c] = bf2f(vb) * rrb[c];
  }
  __syncthreads();
  if (t < 8) {
    float s = 0.f;
    #pragma unroll 16
    for (int i = 0; i < 64; ++i) s += red[t*64 + i];
    c2g[(size_t)t*(2*TT - 1) + m] = s * LOG2E;
  }
}

// ---------------- fused: V transpose tiles | c1[h][row] = (rwb_h . k[row]) * log2e ----------------
__global__ __launch_bounds__(256) void vtrans_c1(
    const ushort* __restrict__ qkv, const float* __restrict__ rwb,
    ushort* __restrict__ vTg, float* __restrict__ c1g)
{
  const int blk = blockIdx.x;
  const int t = threadIdx.x;
  if (blk < 4608) {
    const int bx = (blk % 48) * 32;   // vd base
    const int by = (blk / 48) * 32;   // key base
    const int tx = t & 31, ty = t >> 5;
    __shared__ ushort tile[32][33];
    #pragma unroll
    for (int i = 0; i < 4; ++i)
      tile[ty + i*8][tx] = qkv[(size_t)(by + ty + i*8)*QKVP + 1024 + bx + tx];
    __syncthreads();
    #pragma unroll
    for (int i = 0; i < 4; ++i)
      vTg[(size_t)(bx + ty + i*8)*(BT*TT) + by + tx] = tile[tx][ty + i*8];
  } else {
    const int idx = (blk - 4608)*256 + t;  // 3072*8
    const int h = idx & 7, row = idx >> 3;
    const ushort* kr = &qkv[(size_t)row*QKVP + 512 + h*KD];
    float s = 0.f;
    #pragma unroll 16
    for (int c = 0; c < 64; ++c) s += bf2f(kr[c]) * rwb[h*KD + c];
    c1g[h*(BT*TT) + row] = s * LOG2E;
  }
}

// ---------------- fused relative attention: KBLK=64, counted-vmcnt pipeline, XCD-swizzled grid ----------------
__global__ __launch_bounds__(256, 2) void attn_mfma(
    const ushort* __restrict__ qkv, const ushort* __restrict__ vTg,
    const ushort* __restrict__ rk,
    const float* __restrict__ c1g, const float* __restrict__ c2g,
    ushort* __restrict__ aout)
{
  __shared__ __align__(16) ushort ktL[64*64];
  __shared__ __align__(16) ushort rkbL[96*64];
  __shared__ __align__(16) ushort vTl[192*64];
  __shared__ __align__(16) ushort Pl[32][72];
  __shared__ __align__(16) float S1[32][68];
  __shared__ __align__(16) float S2[32][98];
  __shared__ float corrl[32], linv[32];

  const int t = threadIdx.x;
  const int wv = t >> 6, lane = t & 63;
  const int lrow = lane & 15, lk8 = lane >> 4;
  const int bid = blockIdx.x;
  const int qt = bid >> 4;          // XCD swizzle: bid%8 == h
  const int h  = bid & 7;
  const int b  = (bid >> 3) & 1;
  const int q0 = qt * 32;

  bf16x8 af00, af01, af10, af11;
  {
    const ushort* qbase = &qkv[((size_t)(b*TT) + q0 + lrow)*QKVP + h*KD];
    af00 = *(const bf16x8*)&qbase[lk8*8];
    af01 = *(const bf16x8*)&qbase[32 + lk8*8];
    af10 = *(const bf16x8*)&qbase[16*QKVP + lk8*8];
    af11 = *(const bf16x8*)&qbase[16*QKVP + 32 + lk8*8];
  }

  if (t < 32) ((uint*)rkbL)[95*32 + t] = 0;

  const ushort* ksrc[2]; ushort* kdst[2];
  #pragma unroll
  for (int W = 0; W < 2; ++W) {
    const int c = W*256 + t;
    const int r = c >> 3, cp = c & 7;
    ksrc[W] = qkv + (size_t)(b*TT + r)*QKVP + 512 + h*KD + (cp ^ (r & 7))*8;
    kdst[W] = ktL + c*8;
  }
  const ushort* rsrc[3]; ushort* rdst[3];
  #pragma unroll
  for (int W = 0; W < 3; ++W) {
    const int c = W*256 + t;
    const int r = c >> 3, cp = c & 7;
    rsrc[W] = rk + (size_t)(1504 - q0 + r)*HK + h*KD + (cp ^ (r & 7))*8;
    rdst[W] = rkbL + c*8;
  }
  const bool rval = t < 248;
  const ushort* vsrc[6]; ushort* vdst[6];
  #pragma unroll
  for (int W = 0; W < 6; ++W) {
    const int c = W*256 + t;
    const int vd = c >> 3, cpk = c & 7;
    vsrc[W] = vTg + (size_t)(h*VD + vd)*(BT*TT) + b*TT + (cpk ^ (vd & 7))*8;
    vdst[W] = vTl + c*8;
  }

  int jk_[2], rt1_[2], j2_[3], rt2_[3];
  #pragma unroll
  for (int s = 0; s < 2; ++s) {
    const int idx = wv*2 + s;
    rt1_[s] = idx >> 2; jk_[s] = (idx & 3)*16 + lrow;
  }
  #pragma unroll
  for (int s = 0; s < 3; ++s) {
    const int idx = wv*3 + s;
    rt2_[s] = (idx >= 6) ? 1 : 0; j2_[s] = (idx - 6*rt2_[s])*16 + lrow;
  }

  f32x4 acc[2][3];
  #pragma unroll
  for (int i = 0; i < 2; ++i)
    #pragma unroll
    for (int j = 0; j < 3; ++j) acc[i][j] = (f32x4){0.f, 0.f, 0.f, 0.f};
  float m_i = -1e30f, l_i = 0.f;
  const int r_s = t >> 3;
  const int vsl = t & 7;

  float c1p[2], c2p[3];
  {
    const int mb0 = -q0 + 1504;
    #pragma unroll
    for (int s = 0; s < 2; ++s) c1p[s] = c1g[h*(BT*TT) + b*TT + jk_[s]];
    #pragma unroll
    for (int s = 0; s < 3; ++s) {
      const float v = c2g[(size_t)h*(2*TT - 1) + mb0 + (j2_[s] < 95 ? j2_[s] : 94)];
      c2p[s] = (j2_[s] < 95) ? v : 0.f;
    }
  }
  #pragma unroll
  for (int W = 0; W < 2; ++W) { gload_lds16(ksrc[W], kdst[W]); ksrc[W] += 64*QKVP; }
  gload_lds16(rsrc[0], rdst[0]);           rsrc[0] += 64*HK;
  gload_lds16(rsrc[1], rdst[1]);           rsrc[1] += 64*HK;
  if (rval) gload_lds16(rsrc[2], rdst[2]);
  rsrc[2] += 64*HK;
  #pragma unroll
  for (int W = 0; W < 6; ++W) { gload_lds16(vsrc[W], vdst[W]); vsrc[W] += 64; }

  for (int it = 0; it < 24; ++it) {
    // ==== phase A: S-compute ====
    asm volatile("s_waitcnt vmcnt(6)" ::: "memory");
    __builtin_amdgcn_s_barrier();
    #pragma unroll
    for (int s = 0; s < 2; ++s) {
      const int rt = rt1_[s], jk = jk_[s];
      const bf16x8 a0 = rt ? af10 : af00;
      const bf16x8 a1 = rt ? af11 : af01;
      bf16x8 b0 = *(const bf16x8*)&ktL[jk*64 + ((lk8 ^ (jk & 7)) << 3)];
      bf16x8 b1 = *(const bf16x8*)&ktL[jk*64 + (((lk8 + 4) ^ (jk & 7)) << 3)];
      f32x4 c0 = (f32x4){0.f, 0.f, 0.f, 0.f};
      c0 = mfma_bf(a0, b0, c0);
      c0 = mfma_bf(a1, b1, c0);
      #pragma unroll
      for (int r = 0; r < 4; ++r) S1[rt*16 + lk8*4 + r][jk] = c0[r] + c1p[s];
    }
    #pragma unroll
    for (int s = 0; s < 3; ++s) {
      const int rt = rt2_[s], j2 = j2_[s];
      const bf16x8 a0 = rt ? af10 : af00;
      const bf16x8 a1 = rt ? af11 : af01;
      bf16x8 b0 = *(const bf16x8*)&rkbL[j2*64 + ((lk8 ^ (j2 & 7)) << 3)];
      bf16x8 b1 = *(const bf16x8*)&rkbL[j2*64 + (((lk8 + 4) ^ (j2 & 7)) << 3)];
      f32x4 c0 = (f32x4){0.f, 0.f, 0.f, 0.f};
      c0 = mfma_bf(a0, b0, c0);
      c0 = mfma_bf(a1, b1, c0);
      #pragma unroll
      for (int r = 0; r < 4; ++r) S2[rt*16 + lk8*4 + r][j2] = c0[r] + c2p[s];
    }
    asm volatile("s_waitcnt lgkmcnt(0)" ::: "memory");
    __builtin_amdgcn_s_barrier();

    // ==== phase B: prefetch next k/rkb + c1c2; softmax; retire vT ====
    if (it < 23) {
      #pragma unroll
      for (int W = 0; W < 2; ++W) { gload_lds16(ksrc[W], kdst[W]); ksrc[W] += 64*QKVP; }
      gload_lds16(rsrc[0], rdst[0]);           rsrc[0] += 64*HK;
      gload_lds16(rsrc[1], rdst[1]);           rsrc[1] += 64*HK;
      if (rval) gload_lds16(rsrc[2], rdst[2]);
      rsrc[2] += 64*HK;
      const int kt0n = (it + 1) << 6;
      const int mbn = kt0n - q0 + 1504;
      #pragma unroll
      for (int s = 0; s < 2; ++s) c1p[s] = c1g[h*(BT*TT) + b*TT + kt0n + jk_[s]];
      #pragma unroll
      for (int s = 0; s < 3; ++s) {
        const float v = c2g[(size_t)h*(2*TT - 1) + mbn + (j2_[s] < 95 ? j2_[s] : 94)];
        c2p[s] = (j2_[s] < 95) ? v : 0.f;
      }
    }
    {
      float sv[8];
      #pragma unroll
      for (int i = 0; i < 8; ++i) {
        const int j = vsl*8 + i;
        sv[i] = S1[r_s][j] + S2[r_s][j - r_s + 31];
      }
      float lmax = sv[0];
      #pragma unroll
      for (int i = 1; i < 8; ++i) lmax = fmaxf(lmax, sv[i]);
      #pragma unroll
      for (int s = 1; s < 8; s <<= 1) lmax = fmaxf(lmax, __shfl_xor(lmax, s, 64));
      const bool defer = (lmax <= m_i + 8.0f);
      const float m_new = defer ? m_i : fmaxf(m_i, lmax);
      const float corr  = defer ? 1.0f : exp2f(m_i - m_new);
      float p[8];
      float lsum = 0.f;
      #pragma unroll
      for (int i = 0; i < 8; ++i) { p[i] = exp2f(sv[i] - m_new); lsum += p[i]; }
      uint4 pw;
      pw.x = (uint)f2bf(p[0]) | ((uint)f2bf(p[1]) << 16);
      pw.y = (uint)f2bf(p[2]) | ((uint)f2bf(p[3]) << 16);
      pw.z = (uint)f2bf(p[4]) | ((uint)f2bf(p[5]) << 16);
      pw.w = (uint)f2bf(p[6]) | ((uint)f2bf(p[7]) << 16);
      *(uint4*)&Pl[r_s][vsl*8] = pw;
      #pragma unroll
      for (int s = 1; s < 8; s <<= 1) lsum += __shfl_xor(lsum, s, 64);
      l_i = l_i * corr + lsum;
      m_i = m_new;
      if (vsl == 0) corrl[r_s] = corr;
    }
    if (it < 23) { asm volatile("s_waitcnt vmcnt(10)" ::: "memory"); }
    else         { asm volatile("s_waitcnt vmcnt(0)"  ::: "memory"); }
    asm volatile("s_waitcnt lgkmcnt(0)" ::: "memory");
    __builtin_amdgcn_s_barrier();

    // ==== phase C: PV ====
    {
      bf16x8 pa[2][2], bv[3][2];
      #pragma unroll
      for (int rt = 0; rt < 2; ++rt) {
        pa[rt][0] = *(const bf16x8*)&Pl[rt*16 + lrow][lk8*8];
        pa[rt][1] = *(const bf16x8*)&Pl[rt*16 + lrow][32 + lk8*8];
      }
      #pragma unroll
      for (int cc = 0; cc < 3; ++cc) {
        const int rv = (3*wv + cc)*16 + lrow;
        bv[cc][0] = *(const bf16x8*)&vTl[rv*64 + ((lk8 ^ (rv & 7)) << 3)];
        bv[cc][1] = *(const bf16x8*)&vTl[rv*64 + (((lk8 + 4) ^ (rv & 7)) << 3)];
      }
      float cr[2][4];
      #pragma unroll
      for (int rt = 0; rt < 2; ++rt)
        #pragma unroll
        for (int r = 0; r < 4; ++r) cr[rt][r] = corrl[rt*16 + lk8*4 + r];
      asm volatile("s_waitcnt lgkmcnt(0)" ::: "memory");
      __builtin_amdgcn_s_barrier();
      if (it < 23) {
        #pragma unroll
        for (int W = 0; W < 6; ++W) { gload_lds16(vsrc[W], vdst[W]); vsrc[W] += 64; }
      }
      bool need = false;
      #pragma unroll
      for (int rt = 0; rt < 2; ++rt)
        #pragma unroll
        for (int r = 0; r < 4; ++r) need |= (cr[rt][r] != 1.0f);
      if (__any(need ? 1 : 0)) {
        #pragma unroll
        for (int rt = 0; rt < 2; ++rt)
          #pragma unroll
          for (int cc = 0; cc < 3; ++cc)
            #pragma unroll
            for (int r = 0; r < 4; ++r) acc[rt][cc][r] *= cr[rt][r];
      }
      #pragma unroll
      for (int rt = 0; rt < 2; ++rt)
        #pragma unroll
        for (int cc = 0; cc < 3; ++cc) {
          acc[rt][cc] = mfma_bf(pa[rt][0], bv[cc][0], acc[rt][cc]);
          acc[rt][cc] = mfma_bf(pa[rt][1], bv[cc][1], acc[rt][cc]);
        }
    }
  }
  if (vsl == 0) linv[r_s] = 1.0f / l_i;
  __syncthreads();
  #pragma unroll
  for (int rt = 0; rt < 2; ++rt) {
    #pragma unroll
    for (int cc = 0; cc < 3; ++cc) {
      const int colg = (3*wv + cc)*16 + lrow;
      #pragma unroll
      for (int r = 0; r < 4; ++r) {
        const int rowg = rt*16 + lk8*4 + r;
        aout[((size_t)(b*TT) + q0 + rowg) * HV + h*VD + colg] = f2bf(acc[rt][cc][r] * linv[rowg]);
      }
    }
  }
}

extern "C" void kernel_launch(void* const* d_in, const int* in_sizes, int n_in,
                              void* d_out, int out_size, void* d_ws, size_t ws_size,
                              hipStream_t stream)
{
  const float* X   = (const float*)d_in[0];
  const float* Wq  = (const float*)d_in[1];
  const float* Wk  = (const float*)d_in[2];
  const float* Wv  = (const float*)d_in[3];
  const float* Wrk = (const float*)d_in[4];
  const float* We  = (const float*)d_in[5];
  const float* be  = (const float*)d_in[6];
  const float* rwb = (const float*)d_in[7];
  const float* rrb = (const float*)d_in[8];
  float* out = (float*)d_out;

  char* ws = (char*)d_ws;
  ushort* Xb    = (ushort*)ws;                       ws += (size_t)3072*1536*2;
  ushort* Wqkvt = (ushort*)ws;                       ws += (size_t)2560*1536*2;
  ushort* Wet   = (ushort*)ws;                       ws += (size_t)1536*1536*2;
  float*  S1b   = (float*)ws;                        ws += (size_t)97*512*4;
  float*  S2b   = (float*)ws;                        ws += (size_t)97*512*4;
  ushort* qkvb  = (ushort*)ws;                       ws += (size_t)3072*2560*2;
  ushort* vTgb  = (ushort*)ws;                       ws += (size_t)1536*3072*2;
  ushort* rkb   = (ushort*)ws;                       ws += (size_t)3071*512*2;
  float*  c1g   = (float*)ws;                        ws += (size_t)8*3072*4;
  float*  c2g   = (float*)ws;                        ws += (size_t)8*3071*4;
  ushort* ao    = (ushort*)ws;                       // 3072*1536*2

  dim3 blk(256);
  prep_kernel<<<dim3(8194), blk, 0, stream>>>(X, Wq, Wk, Wv, We, Wrk, Xb, Wqkvt, Wet, S1b, S2b);
  relk_fill<<<dim3(2*TT - 1), blk, 0, stream>>>(S1b, S2b, rrb, rkb, c2g);
  gemm_bf16<false, ushort><<<dim3(20*24), blk, 0, stream>>>(Xb, Wqkvt, nullptr, qkvb, 3072, QKVP, 1536);
  vtrans_c1<<<dim3(4704), blk, 0, stream>>>(qkvb, rwb, vTgb, c1g);
  attn_mfma<<<dim3(BT*HB*(TT/32)), blk, 0, stream>>>(qkvb, vTgb, rkb, c1g, c2g, ao);
  gemm_bf16<true, float><<<dim3(12*24), blk, 0, stream>>>(ao, Wet, be, out, 3072, 1536, 1536);
}

// Round 16
// 199.739 us; speedup vs baseline: 1.3291x; 1.0050x over previous
//
#include <hip/hip_runtime.h>
#include <math.h>

#define HB 8
#define KD 64
#define VD 192
#define BT 2
#define TT 1536
#define CC 1536
#define HK (HB*KD)   // 512
#define HV (HB*VD)   // 1536
#define QKVP 2560    // fused qkv row pitch: q[0:512) k[512:1024) v[1024:2560)
#define LOG2E 1.44269504088896340736f

typedef float f32x4 __attribute__((ext_vector_type(4)));
typedef __bf16 bf16x8 __attribute__((ext_vector_type(8)));

static __device__ __forceinline__ ushort f2bf(float f) {
  union { float f; uint u; } v; v.f = f;
  uint r = (v.u + 0x7FFFu + ((v.u >> 16) & 1u)) >> 16;  // RNE
  return (ushort)r;
}
static __device__ __forceinline__ float bf2f(ushort u) {
  union { uint u; float f; } v; v.u = ((uint)u) << 16; return v.f;
}

static __device__ __forceinline__ f32x4 mfma_bf(bf16x8 a, bf16x8 b, f32x4 c) {
  return __builtin_amdgcn_mfma_f32_16x16x32_bf16(a, b, c, 0, 0, 0);
}

static __device__ __forceinline__ void gload_lds16(const ushort* g, ushort* l) {
  __builtin_amdgcn_global_load_lds(
      (const __attribute__((address_space(1))) unsigned int*)g,
      (__attribute__((address_space(3))) unsigned int*)l, 16, 0, 0);
}

__device__ __forceinline__ void storeC(float* p, float v) { *p = v; }
__device__ __forceinline__ void storeC(ushort* p, float v) { *p = f2bf(v); }

// ---------------- fused prep: cast X->bf16 | Wrk suffix sums | 64x64 transpose+cast ----------------
// blocks [0,2048): cast; [2048,2050): wrk_suffix; [2050,3586): tcast 64x64 tiles
__global__ __launch_bounds__(256) void prep_kernel(
    const float* __restrict__ X,  const float* __restrict__ Wq,
    const float* __restrict__ Wk, const float* __restrict__ Wv,
    const float* __restrict__ We, const float* __restrict__ Wrk,
    ushort* __restrict__ Xb, ushort* __restrict__ Wqkvt, ushort* __restrict__ Wet,
    float* __restrict__ S1b, float* __restrict__ S2b)
{
  const int blk = blockIdx.x;
  const int t = threadIdx.x;
  if (blk < 2048) {
    const int n4 = (3072*1536)/4;
    for (int i = blk*256 + t; i < n4; i += 2048*256) {
      float4 v = ((const float4*)X)[i];
      ushort4 o; o.x = f2bf(v.x); o.y = f2bf(v.y); o.z = f2bf(v.z); o.w = f2bf(v.w);
      ((ushort4*)Xb)[i] = o;
    }
  } else if (blk < 2050) {
    const int c = (blk - 2048)*256 + t;   // 0..511
    float a1 = 0.f, a2 = 0.f;
    S1b[96*HK + c] = 0.f; S2b[96*HK + c] = 0.f;
    for (int i = 95; i >= 0; --i) {
      a1 += Wrk[i*HK + c];
      a2 += Wrk[(96 + i)*HK + c];
      S1b[i*HK + c] = a1; S2b[i*HK + c] = a2;
    }
  } else {
    int u = blk - 2050;
    const float* in; ushort* out; int R, C; float scale; int bxi, byi;
    if (u < 192)       { in = Wq; out = Wqkvt;                      R = 1536; C = 512;  scale = 0.125f*LOG2E; bxi = u & 7;  byi = u >> 3; }
    else if (u < 384)  { u -= 192; in = Wk; out = Wqkvt + (size_t)512*1536;  R = 1536; C = 512;  scale = 1.0f; bxi = u & 7;  byi = u >> 3; }
    else if (u < 960)  { u -= 384; in = Wv; out = Wqkvt + (size_t)1024*1536; R = 1536; C = 1536; scale = 1.0f; bxi = u % 24; byi = u / 24; }
    else               { u -= 960; in = We; out = Wet;              R = 1536; C = 1536; scale = 1.0f; bxi = u % 24; byi = u / 24; }
    const int bx = bxi*64, by = byi*64;
    __shared__ float tile[64][65];
    const int lc = t & 63, lr0 = t >> 6;         // loads: 256B/wave-row, 16 rows/thread-group
    #pragma unroll
    for (int i = 0; i < 16; ++i)
      tile[lr0 + i*4][lc] = in[(size_t)(by + lr0 + i*4)*C + bx + lc];
    __syncthreads();
    const int kc = t & 31, v0 = t >> 5;          // stores: packed 2xbf16
    #pragma unroll
    for (int i = 0; i < 8; ++i) {
      const int v = v0 + i*8;
      const uint uu = (uint)f2bf(tile[kc*2][v] * scale) | ((uint)f2bf(tile[kc*2+1][v] * scale) << 16);
      *(uint*)&out[(size_t)(bx + v)*R + by + kc*2] = uu;
    }
  }
}

// ---------------- bf16 MFMA GEMM: C[M,N] = A[M,Kd] @ Bt[N,Kd]^T (+bias) ----------------
// 1D grid with XCD-aware chunked swizzle (requires gridDim.x % 8 == 0).
template<bool WITH_BIAS, typename OutT>
__global__ __launch_bounds__(256) void gemm_bf16(
    const ushort* __restrict__ A, const ushort* __restrict__ Bt,
    const float* __restrict__ bias, OutT* __restrict__ C,
    int M, int N, int Kd)
{
  __shared__ __align__(16) ushort As[128*64];
  __shared__ __align__(16) ushort Bs[128*64];
  const int t = threadIdx.x;
  const int w = t >> 6, lane = t & 63;
  const int lrow = lane & 15, lk8 = lane >> 4;
  const int nwg = gridDim.x;
  const int qchunk = nwg >> 3;
  const int swz = (blockIdx.x & 7) * qchunk + (blockIdx.x >> 3);
  const int NX = N >> 7;
  const int row0 = (swz / NX) * 128, col0 = (swz % NX) * 128;
  const int wr = (w >> 1) * 64, wc = (w & 1) * 64;

  f32x4 acc[4][4];
  #pragma unroll
  for (int m = 0; m < 4; ++m)
    #pragma unroll
    for (int n = 0; n < 4; ++n) acc[m][n] = (f32x4){0.f,0.f,0.f,0.f};

  for (int k0 = 0; k0 < Kd; k0 += 64) {
    __syncthreads();
    #pragma unroll
    for (int j = 0; j < 4; ++j) {
      const int c = (w*4 + j)*64 + lane;
      const int r = c >> 3, cp = c & 7;
      const int sc = cp ^ (r & 7);
      gload_lds16(A  + (size_t)(row0 + r)*Kd + k0 + sc*8, As + c*8);
      gload_lds16(Bt + (size_t)(col0 + r)*Kd + k0 + sc*8, Bs + c*8);
    }
    __syncthreads();
    bf16x8 af[4][2], bfv[4][2];
    #pragma unroll
    for (int m = 0; m < 4; ++m) {
      const int r = wr + m*16 + lrow;
      #pragma unroll
      for (int kh = 0; kh < 2; ++kh) {
        const int k8 = lk8 + kh*4;
        af[m][kh] = *(const bf16x8*)&As[r*64 + ((k8 ^ (r & 7)) << 3)];
      }
    }
    #pragma unroll
    for (int n = 0; n < 4; ++n) {
      const int r = wc + n*16 + lrow;
      #pragma unroll
      for (int kh = 0; kh < 2; ++kh) {
        const int k8 = lk8 + kh*4;
        bfv[n][kh] = *(const bf16x8*)&Bs[r*64 + ((k8 ^ (r & 7)) << 3)];
      }
    }
    #pragma unroll
    for (int m = 0; m < 4; ++m)
      #pragma unroll
      for (int n = 0; n < 4; ++n) {
        acc[m][n] = mfma_bf(af[m][0], bfv[n][0], acc[m][n]);
        acc[m][n] = mfma_bf(af[m][1], bfv[n][1], acc[m][n]);
      }
  }
  #pragma unroll
  for (int m = 0; m < 4; ++m)
    #pragma unroll
    for (int n = 0; n < 4; ++n) {
      const int cg = col0 + wc + n*16 + lrow;
      const float bb = WITH_BIAS ? bias[cg] : 0.f;
      #pragma unroll
      for (int r = 0; r < 4; ++r) {
        const int rg = row0 + wr + m*16 + lk8*4 + r;
        storeC(&C[(size_t)rg*N + cg], acc[m][n][r] + bb);
      }
    }
}

// ---------------- rk[m][c] bf16 + c2[h][m] = (rrb_h . rk[m]) * log2e ----------------
__global__ __launch_bounds__(256) void relk_fill(
    const float* __restrict__ S1, const float* __restrict__ S2,
    const float* __restrict__ rrb, ushort* __restrict__ rk, float* __restrict__ c2g)
{
  __shared__ float cw[96];
  __shared__ float red[512];
  __shared__ int i0s;
  const int t = threadIdx.x;
  const int m = blockIdx.x;            // 0 .. 2T-2
  if (t < 96) {
    double pr = exp(log((double)(TT + 1)) / 96.0);
    float prf = (float)pr;
    cw[t] = (float)pow((double)prf, (double)(t + 1)) - 1.0f;
  }
  __syncthreads();
  const int d = m - (TT - 1);
  const float ad = fabsf((float)d);
  if (t == 0) {
    int i0 = 96;
    for (int i = 0; i < 96; ++i) if (cw[i] > ad) { i0 = i; break; }
    i0s = i0;
  }
  __syncthreads();
  const float sg = (d > 0) ? 1.f : (d < 0 ? -1.f : 0.f);
  const int i0 = i0s;
  for (int c = t; c < HK; c += 256) {
    const float val = S1[i0*HK + c] + sg * S2[i0*HK + c];
    const ushort vb = f2bf(val);
    rk[(size_t)m * HK + c] = vb;
    red[c] = bf2f(vb) * rrb[c];
  }
  __syncthreads();
  if (t < 8) {
    float s = 0.f;
    #pragma unroll 16
    for (int i = 0; i < 64; ++i) s += red[t*64 + i];
    c2g[(size_t)t*(2*TT - 1) + m] = s * LOG2E;
  }
}

// ---------------- fused: 64x64 V transpose tiles | c1[h][row] = (rwb_h . k[row]) * log2e ----------------
// blocks [0,1152): vtrans 64x64 tiles (24 vd-tiles x 48 key-tiles); [1152,1248): c1
__global__ __launch_bounds__(256) void vtrans_c1(
    const ushort* __restrict__ qkv, const float* __restrict__ rwb,
    ushort* __restrict__ vTg, float* __restrict__ c1g)
{
  const int blk = blockIdx.x;
  const int t = threadIdx.x;
  if (blk < 1152) {
    const int bx = (blk % 24) * 64;   // vd base
    const int by = (blk / 24) * 64;   // key base
    __shared__ ushort tile[64][66];
    const int lc = t & 31, lr0 = t >> 5;   // uint loads: 2 vd-elems/thread
    #pragma unroll
    for (int i = 0; i < 8; ++i) {
      const int row = lr0 + i*8;
      const uint uu = *(const uint*)&qkv[(size_t)(by + row)*QKVP + 1024 + bx + lc*2];
      tile[row][lc*2]   = (ushort)(uu & 0xffff);
      tile[row][lc*2+1] = (ushort)(uu >> 16);
    }
    __syncthreads();
    const int kc = t & 31, v0 = t >> 5;    // uint stores: 2 key-elems/thread
    #pragma unroll
    for (int i = 0; i < 8; ++i) {
      const int v = v0 + i*8;
      const uint uu = (uint)tile[kc*2][v] | ((uint)tile[kc*2+1][v] << 16);
      *(uint*)&vTg[(size_t)(bx + v)*(BT*TT) + by + kc*2] = uu;
    }
  } else {
    const int idx = (blk - 1152)*256 + t;  // 3072*8
    const int h = idx & 7, row = idx >> 3;
    const ushort* kr = &qkv[(size_t)row*QKVP + 512 + h*KD];
    float s = 0.f;
    #pragma unroll 16
    for (int c = 0; c < 64; ++c) s += bf2f(kr[c]) * rwb[h*KD + c];
    c1g[h*(BT*TT) + row] = s * LOG2E;
  }
}

// ---------------- fused relative attention: KBLK=64, counted-vmcnt pipeline, XCD-swizzled grid ----------------
__global__ __launch_bounds__(256, 2) void attn_mfma(
    const ushort* __restrict__ qkv, const ushort* __restrict__ vTg,
    const ushort* __restrict__ rk,
    const float* __restrict__ c1g, const float* __restrict__ c2g,
    ushort* __restrict__ aout)
{
  __shared__ __align__(16) ushort ktL[64*64];
  __shared__ __align__(16) ushort rkbL[96*64];
  __shared__ __align__(16) ushort vTl[192*64];
  __shared__ __align__(16) ushort Pl[32][72];
  __shared__ __align__(16) float S1[32][68];
  __shared__ __align__(16) float S2[32][98];
  __shared__ float corrl[32], linv[32];

  const int t = threadIdx.x;
  const int wv = t >> 6, lane = t & 63;
  const int lrow = lane & 15, lk8 = lane >> 4;
  const int bid = blockIdx.x;
  const int qt = bid >> 4;          // XCD swizzle: bid%8 == h
  const int h  = bid & 7;
  const int b  = (bid >> 3) & 1;
  const int q0 = qt * 32;

  bf16x8 af00, af01, af10, af11;
  {
    const ushort* qbase = &qkv[((size_t)(b*TT) + q0 + lrow)*QKVP + h*KD];
    af00 = *(const bf16x8*)&qbase[lk8*8];
    af01 = *(const bf16x8*)&qbase[32 + lk8*8];
    af10 = *(const bf16x8*)&qbase[16*QKVP + lk8*8];
    af11 = *(const bf16x8*)&qbase[16*QKVP + 32 + lk8*8];
  }

  if (t < 32) ((uint*)rkbL)[95*32 + t] = 0;

  const ushort* ksrc[2]; ushort* kdst[2];
  #pragma unroll
  for (int W = 0; W < 2; ++W) {
    const int c = W*256 + t;
    const int r = c >> 3, cp = c & 7;
    ksrc[W] = qkv + (size_t)(b*TT + r)*QKVP + 512 + h*KD + (cp ^ (r & 7))*8;
    kdst[W] = ktL + c*8;
  }
  const ushort* rsrc[3]; ushort* rdst[3];
  #pragma unroll
  for (int W = 0; W < 3; ++W) {
    const int c = W*256 + t;
    const int r = c >> 3, cp = c & 7;
    rsrc[W] = rk + (size_t)(1504 - q0 + r)*HK + h*KD + (cp ^ (r & 7))*8;
    rdst[W] = rkbL + c*8;
  }
  const bool rval = t < 248;
  const ushort* vsrc[6]; ushort* vdst[6];
  #pragma unroll
  for (int W = 0; W < 6; ++W) {
    const int c = W*256 + t;
    const int vd = c >> 3, cpk = c & 7;
    vsrc[W] = vTg + (size_t)(h*VD + vd)*(BT*TT) + b*TT + (cpk ^ (vd & 7))*8;
    vdst[W] = vTl + c*8;
  }

  int jk_[2], rt1_[2], j2_[3], rt2_[3];
  #pragma unroll
  for (int s = 0; s < 2; ++s) {
    const int idx = wv*2 + s;
    rt1_[s] = idx >> 2; jk_[s] = (idx & 3)*16 + lrow;
  }
  #pragma unroll
  for (int s = 0; s < 3; ++s) {
    const int idx = wv*3 + s;
    rt2_[s] = (idx >= 6) ? 1 : 0; j2_[s] = (idx - 6*rt2_[s])*16 + lrow;
  }

  f32x4 acc[2][3];
  #pragma unroll
  for (int i = 0; i < 2; ++i)
    #pragma unroll
    for (int j = 0; j < 3; ++j) acc[i][j] = (f32x4){0.f, 0.f, 0.f, 0.f};
  float m_i = -1e30f, l_i = 0.f;
  const int r_s = t >> 3;
  const int vsl = t & 7;

  float c1p[2], c2p[3];
  {
    const int mb0 = -q0 + 1504;
    #pragma unroll
    for (int s = 0; s < 2; ++s) c1p[s] = c1g[h*(BT*TT) + b*TT + jk_[s]];
    #pragma unroll
    for (int s = 0; s < 3; ++s) {
      const float v = c2g[(size_t)h*(2*TT - 1) + mb0 + (j2_[s] < 95 ? j2_[s] : 94)];
      c2p[s] = (j2_[s] < 95) ? v : 0.f;
    }
  }
  #pragma unroll
  for (int W = 0; W < 2; ++W) { gload_lds16(ksrc[W], kdst[W]); ksrc[W] += 64*QKVP; }
  gload_lds16(rsrc[0], rdst[0]);           rsrc[0] += 64*HK;
  gload_lds16(rsrc[1], rdst[1]);           rsrc[1] += 64*HK;
  if (rval) gload_lds16(rsrc[2], rdst[2]);
  rsrc[2] += 64*HK;
  #pragma unroll
  for (int W = 0; W < 6; ++W) { gload_lds16(vsrc[W], vdst[W]); vsrc[W] += 64; }

  for (int it = 0; it < 24; ++it) {
    // ==== phase A: S-compute ====
    asm volatile("s_waitcnt vmcnt(6)" ::: "memory");
    __builtin_amdgcn_s_barrier();
    #pragma unroll
    for (int s = 0; s < 2; ++s) {
      const int rt = rt1_[s], jk = jk_[s];
      const bf16x8 a0 = rt ? af10 : af00;
      const bf16x8 a1 = rt ? af11 : af01;
      bf16x8 b0 = *(const bf16x8*)&ktL[jk*64 + ((lk8 ^ (jk & 7)) << 3)];
      bf16x8 b1 = *(const bf16x8*)&ktL[jk*64 + (((lk8 + 4) ^ (jk & 7)) << 3)];
      f32x4 c0 = (f32x4){0.f, 0.f, 0.f, 0.f};
      c0 = mfma_bf(a0, b0, c0);
      c0 = mfma_bf(a1, b1, c0);
      #pragma unroll
      for (int r = 0; r < 4; ++r) S1[rt*16 + lk8*4 + r][jk] = c0[r] + c1p[s];
    }
    #pragma unroll
    for (int s = 0; s < 3; ++s) {
      const int rt = rt2_[s], j2 = j2_[s];
      const bf16x8 a0 = rt ? af10 : af00;
      const bf16x8 a1 = rt ? af11 : af01;
      bf16x8 b0 = *(const bf16x8*)&rkbL[j2*64 + ((lk8 ^ (j2 & 7)) << 3)];
      bf16x8 b1 = *(const bf16x8*)&rkbL[j2*64 + (((lk8 + 4) ^ (j2 & 7)) << 3)];
      f32x4 c0 = (f32x4){0.f, 0.f, 0.f, 0.f};
      c0 = mfma_bf(a0, b0, c0);
      c0 = mfma_bf(a1, b1, c0);
      #pragma unroll
      for (int r = 0; r < 4; ++r) S2[rt*16 + lk8*4 + r][j2] = c0[r] + c2p[s];
    }
    asm volatile("s_waitcnt lgkmcnt(0)" ::: "memory");
    __builtin_amdgcn_s_barrier();

    // ==== phase B: prefetch next k/rkb + c1c2; softmax; retire vT ====
    if (it < 23) {
      #pragma unroll
      for (int W = 0; W < 2; ++W) { gload_lds16(ksrc[W], kdst[W]); ksrc[W] += 64*QKVP; }
      gload_lds16(rsrc[0], rdst[0]);           rsrc[0] += 64*HK;
      gload_lds16(rsrc[1], rdst[1]);           rsrc[1] += 64*HK;
      if (rval) gload_lds16(rsrc[2], rdst[2]);
      rsrc[2] += 64*HK;
      const int kt0n = (it + 1) << 6;
      const int mbn = kt0n - q0 + 1504;
      #pragma unroll
      for (int s = 0; s < 2; ++s) c1p[s] = c1g[h*(BT*TT) + b*TT + kt0n + jk_[s]];
      #pragma unroll
      for (int s = 0; s < 3; ++s) {
        const float v = c2g[(size_t)h*(2*TT - 1) + mbn + (j2_[s] < 95 ? j2_[s] : 94)];
        c2p[s] = (j2_[s] < 95) ? v : 0.f;
      }
    }
    {
      float sv[8];
      #pragma unroll
      for (int i = 0; i < 8; ++i) {
        const int j = vsl*8 + i;
        sv[i] = S1[r_s][j] + S2[r_s][j - r_s + 31];
      }
      float lmax = sv[0];
      #pragma unroll
      for (int i = 1; i < 8; ++i) lmax = fmaxf(lmax, sv[i]);
      #pragma unroll
      for (int s = 1; s < 8; s <<= 1) lmax = fmaxf(lmax, __shfl_xor(lmax, s, 64));
      const bool defer = (lmax <= m_i + 8.0f);
      const float m_new = defer ? m_i : fmaxf(m_i, lmax);
      const float corr  = defer ? 1.0f : exp2f(m_i - m_new);
      float p[8];
      float lsum = 0.f;
      #pragma unroll
      for (int i = 0; i < 8; ++i) { p[i] = exp2f(sv[i] - m_new); lsum += p[i]; }
      uint4 pw;
      pw.x = (uint)f2bf(p[0]) | ((uint)f2bf(p[1]) << 16);
      pw.y = (uint)f2bf(p[2]) | ((uint)f2bf(p[3]) << 16);
      pw.z = (uint)f2bf(p[4]) | ((uint)f2bf(p[5]) << 16);
      pw.w = (uint)f2bf(p[6]) | ((uint)f2bf(p[7]) << 16);
      *(uint4*)&Pl[r_s][vsl*8] = pw;
      #pragma unroll
      for (int s = 1; s < 8; s <<= 1) lsum += __shfl_xor(lsum, s, 64);
      l_i = l_i * corr + lsum;
      m_i = m_new;
      if (vsl == 0) corrl[r_s] = corr;
    }
    if (it < 23) { asm volatile("s_waitcnt vmcnt(10)" ::: "memory"); }
    else         { asm volatile("s_waitcnt vmcnt(0)"  ::: "memory"); }
    asm volatile("s_waitcnt lgkmcnt(0)" ::: "memory");
    __builtin_amdgcn_s_barrier();

    // ==== phase C: PV ====
    {
      bf16x8 pa[2][2], bv[3][2];
      #pragma unroll
      for (int rt = 0; rt < 2; ++rt) {
        pa[rt][0] = *(const bf16x8*)&Pl[rt*16 + lrow][lk8*8];
        pa[rt][1] = *(const bf16x8*)&Pl[rt*16 + lrow][32 + lk8*8];
      }
      #pragma unroll
      for (int cc = 0; cc < 3; ++cc) {
        const int rv = (3*wv + cc)*16 + lrow;
        bv[cc][0] = *(const bf16x8*)&vTl[rv*64 + ((lk8 ^ (rv & 7)) << 3)];
        bv[cc][1] = *(const bf16x8*)&vTl[rv*64 + (((lk8 + 4) ^ (rv & 7)) << 3)];
      }
      float cr[2][4];
      #pragma unroll
      for (int rt = 0; rt < 2; ++rt)
        #pragma unroll
        for (int r = 0; r < 4; ++r) cr[rt][r] = corrl[rt*16 + lk8*4 + r];
      asm volatile("s_waitcnt lgkmcnt(0)" ::: "memory");
      __builtin_amdgcn_s_barrier();
      if (it < 23) {
        #pragma unroll
        for (int W = 0; W < 6; ++W) { gload_lds16(vsrc[W], vdst[W]); vsrc[W] += 64; }
      }
      bool need = false;
      #pragma unroll
      for (int rt = 0; rt < 2; ++rt)
        #pragma unroll
        for (int r = 0; r < 4; ++r) need |= (cr[rt][r] != 1.0f);
      if (__any(need ? 1 : 0)) {
        #pragma unroll
        for (int rt = 0; rt < 2; ++rt)
          #pragma unroll
          for (int cc = 0; cc < 3; ++cc)
            #pragma unroll
            for (int r = 0; r < 4; ++r) acc[rt][cc][r] *= cr[rt][r];
      }
      #pragma unroll
      for (int rt = 0; rt < 2; ++rt)
        #pragma unroll
        for (int cc = 0; cc < 3; ++cc) {
          acc[rt][cc] = mfma_bf(pa[rt][0], bv[cc][0], acc[rt][cc]);
          acc[rt][cc] = mfma_bf(pa[rt][1], bv[cc][1], acc[rt][cc]);
        }
    }
  }
  if (vsl == 0) linv[r_s] = 1.0f / l_i;
  __syncthreads();
  #pragma unroll
  for (int rt = 0; rt < 2; ++rt) {
    #pragma unroll
    for (int cc = 0; cc < 3; ++cc) {
      const int colg = (3*wv + cc)*16 + lrow;
      #pragma unroll
      for (int r = 0; r < 4; ++r) {
        const int rowg = rt*16 + lk8*4 + r;
        aout[((size_t)(b*TT) + q0 + rowg) * HV + h*VD + colg] = f2bf(acc[rt][cc][r] * linv[rowg]);
      }
    }
  }
}

extern "C" void kernel_launch(void* const* d_in, const int* in_sizes, int n_in,
                              void* d_out, int out_size, void* d_ws, size_t ws_size,
                              hipStream_t stream)
{
  const float* X   = (const float*)d_in[0];
  const float* Wq  = (const float*)d_in[1];
  const float* Wk  = (const float*)d_in[2];
  const float* Wv  = (const float*)d_in[3];
  const float* Wrk = (const float*)d_in[4];
  const float* We  = (const float*)d_in[5];
  const float* be  = (const float*)d_in[6];
  const float* rwb = (const float*)d_in[7];
  const float* rrb = (const float*)d_in[8];
  float* out = (float*)d_out;

  char* ws = (char*)d_ws;
  ushort* Xb    = (ushort*)ws;                       ws += (size_t)3072*1536*2;
  ushort* Wqkvt = (ushort*)ws;                       ws += (size_t)2560*1536*2;
  ushort* Wet   = (ushort*)ws;                       ws += (size_t)1536*1536*2;
  float*  S1b   = (float*)ws;                        ws += (size_t)97*512*4;
  float*  S2b   = (float*)ws;                        ws += (size_t)97*512*4;
  ushort* qkvb  = (ushort*)ws;                       ws += (size_t)3072*2560*2;
  ushort* vTgb  = (ushort*)ws;                       ws += (size_t)1536*3072*2;
  ushort* rkb   = (ushort*)ws;                       ws += (size_t)3071*512*2;
  float*  c1g   = (float*)ws;                        ws += (size_t)8*3072*4;
  float*  c2g   = (float*)ws;                        ws += (size_t)8*3071*4;
  ushort* ao    = (ushort*)ws;                       // 3072*1536*2

  dim3 blk(256);
  prep_kernel<<<dim3(3586), blk, 0, stream>>>(X, Wq, Wk, Wv, We, Wrk, Xb, Wqkvt, Wet, S1b, S2b);
  relk_fill<<<dim3(2*TT - 1), blk, 0, stream>>>(S1b, S2b, rrb, rkb, c2g);
  gemm_bf16<false, ushort><<<dim3(20*24), blk, 0, stream>>>(Xb, Wqkvt, nullptr, qkvb, 3072, QKVP, 1536);
  vtrans_c1<<<dim3(1248), blk, 0, stream>>>(qkvb, rwb, vTgb, c1g);
  attn_mfma<<<dim3(BT*HB*(TT/32)), blk, 0, stream>>>(qkvb, vTgb, rkb, c1g, c2g, ao);
  gemm_bf16<true, float><<<dim3(12*24), blk, 0, stream>>>(ao, Wet, be, out, 3072, 1536, 1536);
}